// Round 7
// baseline (367.271 us; speedup 1.0000x reference)
//
#include <hip/hip_runtime.h>
#include <hip/hip_bf16.h>

#define NN 50000
#define NE 600000
#define IND 16
#define EDD 8
#define HIDD 128
#define NH 4
#define CC 32
#define EMBD 64
#define FEATD 64
#define NB_SCAN ((NN + 255) / 256)  // 196
#define FILLB ((NE + 255) / 256)    // 2344
#define BZB (NN / 16)               // 3125
#define WPB 256
#define PRMF 896                     // per-layer float param stride
#define NPG 4                        // node-pairs per wave (gat)

typedef __hip_bfloat16 bf16;
typedef __attribute__((ext_vector_type(8))) short bshort8;
typedef __attribute__((ext_vector_type(4))) float floatx4;
typedef __attribute__((ext_vector_type(2))) float f32x2;

// round-to-nearest-even f32 -> bf16 bits
__device__ __forceinline__ unsigned short f2bu(float f) {
    unsigned int u = __float_as_uint(f);
    u += 0x7fffu + ((u >> 16) & 1u);
    return (unsigned short)(u >> 16);
}

// packed bf16x2 dot product with f32 accumulator: a0*b0 + a1*b1 + c
#if defined(__has_builtin)
#if __has_builtin(__builtin_amdgcn_fdot2_f32_bf16)
#define HAS_DOT2BF 1
#endif
#endif
#ifndef HAS_DOT2BF
#define HAS_DOT2BF 0
#endif

#if HAS_DOT2BF
typedef __attribute__((ext_vector_type(2))) __bf16 bfx2;
__device__ __forceinline__ float dot2bf(unsigned int a, unsigned int b, float c) {
    return __builtin_amdgcn_fdot2_f32_bf16(__builtin_bit_cast(bfx2, a),
                                           __builtin_bit_cast(bfx2, b), c, false);
}
#else
__device__ __forceinline__ float dot2bf(unsigned int a, unsigned int b, float c) {
    float a0 = __uint_as_float(a << 16), a1 = __uint_as_float(a & 0xffff0000u);
    float b0 = __uint_as_float(b << 16), b1 = __uint_as_float(b & 0xffff0000u);
    return __builtin_fmaf(a1, b1, __builtin_fmaf(a0, b0, c));
}
#endif

template <bool F32>
__device__ __forceinline__ float LD(const void* p, long long i) {
    if constexpr (F32) return ((const float*)p)[i];
    else return __bfloat162float(((const bf16*)p)[i]);
}

__device__ __forceinline__ bool is_f32(const int* cnt) { return *cnt > 8; }

// ---- merged: dtype detect (block 0, LDS reduce, no atomics) + zero deg/dcnt/ticket
__global__ void k_detinit(const unsigned short* __restrict__ x, int nhalf,
                          int* __restrict__ cnt, int* __restrict__ deg,
                          int* __restrict__ dcnt) {
    if (blockIdx.x == 0) {
        __shared__ int red[256];
        int hits = 0;
        for (int i = threadIdx.x; i < nhalf; i += 256)
            if ((x[i] & 0x7F80u) == 0x7F80u) hits++;
        red[threadIdx.x] = hits;
        __syncthreads();
        for (int o = 128; o; o >>= 1) {
            if (threadIdx.x < o) red[threadIdx.x] += red[threadIdx.x + o];
            __syncthreads();
        }
        if (threadIdx.x == 0) *cnt = red[0];
    } else {
        int gid = (blockIdx.x - 1) * 256 + threadIdx.x;
        if (gid < NN) deg[gid] = 0;
        if (blockIdx.x == 1 && threadIdx.x < 80) dcnt[threadIdx.x] = 0;  // 64 buckets + ticket
    }
}

// ---- CSR: histogram also records each edge's rank within its dst bucket
__global__ void k_hist(const int* __restrict__ ei, int* __restrict__ deg, int* __restrict__ rank) {
    int e = blockIdx.x * blockDim.x + threadIdx.x;
    if (e < NE) rank[e] = atomicAdd(&deg[ei[NE + e]], 1);
}

// Degree buckets REVERSED (b = 63 - min(deg,63)): longest blocks dispatch first.
// FUSED scan level 1 + level 2 (last-block-ticket). Cross-block-communicated
// values (bsum) use atomicExch/atomicAdd(p,0) for device-coherent access
// (per-XCD L2s are not coherent for plain load/store).
__global__ void k_scan12(const int* __restrict__ deg, int* __restrict__ off0,
                         int* __restrict__ bsum, int* __restrict__ dcnt,
                         int* __restrict__ dbase, int* __restrict__ rankd) {
    __shared__ int tile[256];
    __shared__ int lh[64];
    __shared__ int lbase[64];
    __shared__ int d2[64];
    __shared__ int ticket;
    int t = threadIdx.x;
    int gid = blockIdx.x * 256 + t;
    if (t < 64) lh[t] = 0;
    __syncthreads();
    int v = (gid < NN) ? deg[gid] : 0;
    int b = 63 - min(v, 63);
    int lr = 0;
    if (gid < NN) lr = atomicAdd(&lh[b], 1);
    tile[t] = v;
    __syncthreads();
    if (t < 64) lbase[t] = lh[t] ? atomicAdd(&dcnt[t], lh[t]) : 0;
    #pragma unroll
    for (int o = 1; o < 256; o <<= 1) {
        int u = (t >= o) ? tile[t - o] : 0;
        __syncthreads();
        tile[t] += u;
        __syncthreads();
    }
    if (gid < NN) {
        off0[gid] = tile[t] - v;
        rankd[gid] = lbase[b] + lr;
    }
    if (t == 255) atomicExch(&bsum[blockIdx.x], tile[255]);  // coherent publish
    __syncthreads();
    if (t == 0) ticket = atomicAdd(&dcnt[64], 1);
    __syncthreads();
    if (ticket != NB_SCAN - 1) return;
    // last block: scan bsum (196) and dcnt (64) exclusively
    int v2 = (t < NB_SCAN) ? atomicAdd(&bsum[t], 0) : 0;    // coherent read
    int dv = (t < 64) ? atomicAdd(&dcnt[t], 0) : 0;
    tile[t] = v2;
    if (t < 64) d2[t] = dv;
    __syncthreads();
    #pragma unroll
    for (int o = 1; o < 256; o <<= 1) {
        int u = (t >= o) ? tile[t - o] : 0;
        __syncthreads();
        tile[t] += u;
        __syncthreads();
    }
    #pragma unroll
    for (int o = 1; o < 64; o <<= 1) {
        int u = (t >= o && t < 64) ? d2[t - o] : 0;
        __syncthreads();
        if (t < 64) d2[t] += u;
        __syncthreads();
    }
    if (t < NB_SCAN) bsum[t] = tile[t] - v2;   // consumed after launch boundary (k_prep)
    if (t < 64) dbase[t] = d2[t] - dv;
}

// ---- MERGED prep kernel (one launch):
//  blocks [0, NB_SCAN)                    : scan3 — offF = off0+bsum, perm scatter
//  blocks [NB_SCAN, +FILLB)               : fill — CSR scatter of esrc/ea8
//  blocks [.., +BZB)                      : build_z, 16 nodes/block
//  blocks [.., +WPB)                      : wbT/bias transpose prep (2 halves/block)
//  last 2 blocks                          : packed GAT params (wep/prm), 1/layer
template <bool F32>
__device__ void prep_impl(const int* __restrict__ off0, const int* __restrict__ bsum,
                          const int* __restrict__ deg, const int* __restrict__ rankd,
                          const int* __restrict__ dbase, int* __restrict__ perm,
                          int* __restrict__ offF,
                          const int* __restrict__ ei, const int* __restrict__ rank,
                          int* __restrict__ esrc, uint4* __restrict__ ea8, const void* ea,
                          const void* x, const int* __restrict__ node_idx, const void* emb,
                          const void* W_in, const void* b_in, bf16* __restrict__ zb,
                          const void* Wl1, const void* bl1, const void* Wr1, const void* br1,
                          const void* Wl2, const void* bl2, const void* Wr2, const void* br2,
                          bf16* __restrict__ wbT, float* __restrict__ bias,
                          const void* We1, const void* att1, const void* be1, const void* bo1,
                          const void* g1, const void* beta1,
                          const void* We2, const void* att2, const void* be2, const void* bo2,
                          const void* g2, const void* beta2,
                          const void* Wo, const void* bout,
                          unsigned int* __restrict__ wep, float* __restrict__ prm) {
    int b = blockIdx.x;
    int t = threadIdx.x;
    if (b < NB_SCAN) {
        int gid = b * 256 + t;
        if (gid < NN) {
            offF[gid] = off0[gid] + bsum[b];
            int bk = 63 - min(deg[gid], 63);
            perm[dbase[bk] + rankd[gid]] = gid;
        }
        if (gid == 0) offF[NN] = NE;
    } else if (b < NB_SCAN + FILLB) {
        int e = (b - NB_SCAN) * 256 + t;
        if (e >= NE) return;
        if (e < 16) {
            esrc[NE + e] = 0;
            uint4 z; z.x = 0; z.y = 0; z.z = 0; z.w = 0;
            ea8[NE + e] = z;
        }
        int dst = ei[NE + e];
        int slot = off0[dst] + bsum[dst >> 8] + rank[e];
        esrc[slot] = ei[e];
        uint4 v;
        if constexpr (F32) {
            const float4* ef = (const float4*)ea;
            float4 f0 = ef[2 * e], f1 = ef[2 * e + 1];
            v.x = (unsigned int)f2bu(f0.x) | ((unsigned int)f2bu(f0.y) << 16);
            v.y = (unsigned int)f2bu(f0.z) | ((unsigned int)f2bu(f0.w) << 16);
            v.z = (unsigned int)f2bu(f1.x) | ((unsigned int)f2bu(f1.y) << 16);
            v.w = (unsigned int)f2bu(f1.z) | ((unsigned int)f2bu(f1.w) << 16);
        } else {
            v = ((const uint4*)ea)[e];  // bf16 pairs already packed
        }
        ea8[slot] = v;
    } else if (b < NB_SCAN + FILLB + BZB) {
        int nb = (b - NB_SCAN - FILLB) * 16 + (t >> 7) * 8;
        int t7 = t & 127;
        if (t7 < FEATD) {  // input projection, weights hoisted to regs
            float w[IND];
            #pragma unroll
            for (int k = 0; k < IND; k++) w[k] = LD<F32>(W_in, k * FEATD + t7);
            float bi = LD<F32>(b_in, t7);
            #pragma unroll 2
            for (int nd = 0; nd < 8; nd++) {
                int n = nb + nd;
                float acc = bi;
                #pragma unroll
                for (int k = 0; k < IND; k++)
                    acc += LD<F32>(x, (long long)n * IND + k) * w[k];
                zb[n * HIDD + t7] = __float2bfloat16(fmaxf(acc, 0.f));
            }
        } else {          // station-embedding gather
            #pragma unroll 2
            for (int nd = 0; nd < 8; nd++) {
                int n = nb + nd;
                zb[n * HIDD + t7] = __float2bfloat16(
                    LD<F32>(emb, (long long)node_idx[n] * EMBD + (t7 - FEATD)));
            }
        }
    } else if (b < NB_SCAN + FILLB + BZB + WPB) {
        int bid2 = (b - NB_SCAN - FILLB - BZB) * 2 + (t >> 7);
        int layer = bid2 >> 8;
        int n2 = bid2 & 255;
        int t7 = t & 127;
        const void* W = layer ? (n2 < HIDD ? Wl2 : Wr2) : (n2 < HIDD ? Wl1 : Wr1);
        const void* bb = layer ? (n2 < HIDD ? bl2 : br2) : (n2 < HIDD ? bl1 : br1);
        int nn = n2 & (HIDD - 1);
        wbT[(layer * 256 + n2) * HIDD + t7] = __float2bfloat16(LD<F32>(W, t7 * HIDD + nn));
        if (t7 == 0) bias[layer * 256 + n2] = LD<F32>(bb, nn);
    } else {
        int layer = b - (NB_SCAN + FILLB + BZB + WPB);
        const void* We = layer ? We2 : We1;
        const void* att = layer ? att2 : att1;
        const void* be = layer ? be2 : be1;
        const void* bo = layer ? bo2 : bo1;
        const void* g  = layer ? g2 : g1;
        const void* bt = layer ? beta2 : beta1;
        if (t < 128) {
            // wep[layer][lane5*16 + p*4 + j] = pack(We[2p][c0+j], We[2p+1][c0+j])
            int lane5 = t >> 2, j = t & 3, c0 = lane5 * 4;
            #pragma unroll
            for (int p = 0; p < 4; p++) {
                unsigned int lo_ = f2bu(LD<F32>(We, (2 * p) * HIDD + c0 + j));
                unsigned int hi_ = f2bu(LD<F32>(We, (2 * p + 1) * HIDD + c0 + j));
                wep[layer * 512 + lane5 * 16 + p * 4 + j] = lo_ | (hi_ << 16);
            }
        } else {
            int t2 = t - 128;
            float* Pp = prm + layer * PRMF;
            Pp[t2]        = LD<F32>(att, t2) * 1.4426950408889634f;  // att*log2e
            Pp[128 + t2]  = LD<F32>(be, t2);
            Pp[256 + t2]  = LD<F32>(bo, t2);
            Pp[384 + t2]  = LD<F32>(g, t2);
            Pp[512 + t2]  = LD<F32>(bt, t2);
            if (layer) {
                Pp[640 + t2] = LD<F32>(Wo, t2);
                if (t2 == 0) Pp[768] = LD<F32>(bout, 0);
            }
        }
    }
}
__global__ void k_prep(const int* cnt, const int* off0, const int* bsum, const int* deg,
                       const int* rankd, const int* dbase, int* perm, int* offF,
                       const int* ei, const int* rank, int* esrc, uint4* ea8, const void* ea,
                       const void* x, const int* node_idx, const void* emb,
                       const void* W_in, const void* b_in, bf16* zb,
                       const void* Wl1, const void* bl1, const void* Wr1, const void* br1,
                       const void* Wl2, const void* bl2, const void* Wr2, const void* br2,
                       bf16* wbT, float* bias,
                       const void* We1, const void* att1, const void* be1, const void* bo1,
                       const void* g1, const void* beta1,
                       const void* We2, const void* att2, const void* be2, const void* bo2,
                       const void* g2, const void* beta2,
                       const void* Wo, const void* bout,
                       unsigned int* wep, float* prm) {
    if (is_f32(cnt))
        prep_impl<true>(off0, bsum, deg, rankd, dbase, perm, offF, ei, rank, esrc, ea8, ea,
                        x, node_idx, emb, W_in, b_in, zb, Wl1, bl1, Wr1, br1,
                        Wl2, bl2, Wr2, br2, wbT, bias, We1, att1, be1, bo1, g1, beta1,
                        We2, att2, be2, bo2, g2, beta2, Wo, bout, wep, prm);
    else
        prep_impl<false>(off0, bsum, deg, rankd, dbase, perm, offF, ei, rank, esrc, ea8, ea,
                         x, node_idx, emb, W_in, b_in, zb, Wl1, bl1, Wr1, br1,
                         Wl2, bl2, Wr2, br2, wbT, bias, We1, att1, be1, bo1, g1, beta1,
                         We2, att2, be2, bo2, g2, beta2, Wo, bout, wep, prm);
}

// ---- MFMA projection, SWAPPED operands: D[channel][node] = W·zb^T.
// Each lane holds 4 CONSECUTIVE channels of one node -> single 8B store.
// 64 nodes per block (4 node-tiles), weight fragments loaded once per wave.
__global__ __launch_bounds__(256) void k_projmm(const bf16* __restrict__ zb,
                                                const bf16* __restrict__ wbT,
                                                const float* __restrict__ bias,
                                                bf16* __restrict__ xl, bf16* __restrict__ xr) {
    int wave = threadIdx.x >> 6, lane = threadIdx.x & 63;
    int n0 = wave * 64;             // output-channel base (0..255)
    int l15 = lane & 15, q = lane >> 4;
    bshort8 afr[4][4];  // [j][s]: A rows = channels n0+j*16+l15, k-slice s*32+q*8
    #pragma unroll
    for (int j = 0; j < 4; j++)
        #pragma unroll
        for (int s = 0; s < 4; s++)
            afr[j][s] = *(const bshort8*)(wbT + ((n0 + j * 16 + l15) << 7) + s * 32 + q * 8);
    float4 bias4[4];
    #pragma unroll
    for (int j = 0; j < 4; j++) bias4[j] = *(const float4*)(bias + n0 + j * 16 + q * 4);
    bf16* dst = (n0 < HIDD) ? xl : xr;
    int cbase = (n0 & (HIDD - 1)) + q * 4;
    int nodeBase = blockIdx.x * 64;
    #pragma unroll
    for (int mt = 0; mt < 4; mt++) {
        int node = nodeBase + mt * 16 + l15;
        const bf16* brow = zb + (node << 7) + q * 8;  // OOB rows read into xl region (safe)
        bshort8 bfrag[4];
        #pragma unroll
        for (int s = 0; s < 4; s++) bfrag[s] = *(const bshort8*)(brow + s * 32);
        floatx4 acc0 = {0.f, 0.f, 0.f, 0.f}, acc1 = acc0, acc2 = acc0, acc3 = acc0;
        #pragma unroll
        for (int s = 0; s < 4; s++) {
            acc0 = __builtin_amdgcn_mfma_f32_16x16x32_bf16(afr[0][s], bfrag[s], acc0, 0, 0, 0);
            acc1 = __builtin_amdgcn_mfma_f32_16x16x32_bf16(afr[1][s], bfrag[s], acc1, 0, 0, 0);
            acc2 = __builtin_amdgcn_mfma_f32_16x16x32_bf16(afr[2][s], bfrag[s], acc2, 0, 0, 0);
            acc3 = __builtin_amdgcn_mfma_f32_16x16x32_bf16(afr[3][s], bfrag[s], acc3, 0, 0, 0);
        }
        if (node < NN) {
            floatx4 accs[4] = {acc0, acc1, acc2, acc3};
            #pragma unroll
            for (int j = 0; j < 4; j++) {
                float4 bv = bias4[j];
                uint2 pk;
                pk.x = (unsigned int)f2bu(accs[j][0] + bv.x) |
                       ((unsigned int)f2bu(accs[j][1] + bv.y) << 16);
                pk.y = (unsigned int)f2bu(accs[j][2] + bv.z) |
                       ((unsigned int)f2bu(accs[j][3] + bv.w) << 16);
                *(uint2*)(dst + (node << 7) + cbase + j * 16) = pk;
            }
        }
    }
}

// ---- per-edge compute body (half-wave: 32 lanes, 4 ch/lane, 8-lane head groups)
__device__ __forceinline__ void edge_body(uint4 eu, uint2 xu, const unsigned int (*wp)[4],
                                          const float* base, const f32x2* at2,
                                          float mask, f32x2* acc, float& den) {
    f32x2 xv0, xv1;
    xv0.x = __uint_as_float(xu.x << 16); xv0.y = __uint_as_float(xu.x & 0xffff0000u);
    xv1.x = __uint_as_float(xu.y << 16); xv1.y = __uint_as_float(xu.y & 0xffff0000u);
    f32x2 e01, e23;
    {
        float c0 = base[0];
        c0 = dot2bf(eu.x, wp[0][0], c0);
        c0 = dot2bf(eu.y, wp[1][0], c0);
        c0 = dot2bf(eu.z, wp[2][0], c0);
        c0 = dot2bf(eu.w, wp[3][0], c0);
        float c1 = base[1];
        c1 = dot2bf(eu.x, wp[0][1], c1);
        c1 = dot2bf(eu.y, wp[1][1], c1);
        c1 = dot2bf(eu.z, wp[2][1], c1);
        c1 = dot2bf(eu.w, wp[3][1], c1);
        e01.x = c0; e01.y = c1;
        float c2 = base[2];
        c2 = dot2bf(eu.x, wp[0][2], c2);
        c2 = dot2bf(eu.y, wp[1][2], c2);
        c2 = dot2bf(eu.z, wp[2][2], c2);
        c2 = dot2bf(eu.w, wp[3][2], c2);
        float c3 = base[3];
        c3 = dot2bf(eu.x, wp[0][3], c3);
        c3 = dot2bf(eu.y, wp[1][3], c3);
        c3 = dot2bf(eu.z, wp[2][3], c3);
        c3 = dot2bf(eu.w, wp[3][3], c3);
        e23.x = c2; e23.y = c3;
    }
    f32x2 s0 = xv0 + e01;
    f32x2 s1 = xv1 + e23;
    s0 = __builtin_elementwise_max(s0, s0 * 0.2f);  // leakyrelu (packed)
    s1 = __builtin_elementwise_max(s1, s1 * 0.2f);
    f32x2 lsv = s0 * at2[0] + s1 * at2[1];
    float ls = lsv.x + lsv.y;
    ls += __shfl_xor(ls, 1);
    ls += __shfl_xor(ls, 2);
    ls += __shfl_xor(ls, 4);   // 8-lane head group = 32 channels
    float ex = exp2f(ls) * mask;  // att pre-scaled by log2e
    acc[0] += ex * xv0;
    acc[1] += ex * xv1;
    den += ex;
}

// ---- fused GAT layer: NPG node-pairs per wave processed sequentially
// (degree-matched via global-sort perm; edge-loop weights wp/at2/bev loaded
// ONCE per wave and reused across pairs -> amortized prologue, 4x fewer
// blocks, less block churn). Per node: 2-edge ILP, 3-level rotating prefetch
// (xl 2 iters ahead, esrc/ea8 3 iters ahead; pads NE..NE+15). Barrier-free LN.
// LAST fuses the output head.
template <bool LAST>
__device__ __forceinline__ void gat_impl(const int* __restrict__ perm,
                         const int* __restrict__ off, const int* __restrict__ esrc,
                         const uint4* __restrict__ ea8,
                         const unsigned int* __restrict__ wep,
                         const float* __restrict__ P,
                         const bf16* __restrict__ xl, const bf16* __restrict__ xr,
                         bf16* __restrict__ zb, void* out, bool f32out) {
    int wave = threadIdx.x >> 6;
    int half = (threadIdx.x >> 5) & 1;
    int lane5 = threadIdx.x & 31;
    int c0 = lane5 << 2;  // 4 channels c0..c0+3 ; head = lane5>>3
    unsigned int wp[4][4];
    {
        const uint4* w4 = (const uint4*)(wep + lane5 * 16);
        uint4 wa = w4[0], wb = w4[1], wc = w4[2], wd = w4[3];
        wp[0][0] = wa.x; wp[0][1] = wa.y; wp[0][2] = wa.z; wp[0][3] = wa.w;
        wp[1][0] = wb.x; wp[1][1] = wb.y; wp[1][2] = wb.z; wp[1][3] = wb.w;
        wp[2][0] = wc.x; wp[2][1] = wc.y; wp[2][2] = wc.z; wp[2][3] = wc.w;
        wp[3][0] = wd.x; wp[3][1] = wd.y; wp[3][2] = wd.z; wp[3][3] = wd.w;
    }
    float4 atv = *(const float4*)(P + c0);
    f32x2 at2[2];
    at2[0].x = atv.x; at2[0].y = atv.y;
    at2[1].x = atv.z; at2[1].y = atv.w;
    float4 bev = *(const float4*)(P + 128 + c0);
    int pbase = blockIdx.x * (8 * NPG) + wave * (2 * NPG) + half;
    for (int grp = 0; grp < NPG; grp++) {
        int pidx = pbase + grp * 2;
        if (pidx >= NN) continue;
        int n = perm[pidx];
        uint2 xru = *(const uint2*)(xr + (n << 7) + c0);
        float base[4];
        base[0] = bev.x + __uint_as_float(xru.x << 16);
        base[1] = bev.y + __uint_as_float(xru.x & 0xffff0000u);
        base[2] = bev.z + __uint_as_float(xru.y << 16);
        base[3] = bev.w + __uint_as_float(xru.y & 0xffff0000u);
        int lo = off[n], hi = off[n + 1];
        f32x2 accA[2] = {{0.f, 0.f}, {0.f, 0.f}}, accB[2] = {{0.f, 0.f}, {0.f, 0.f}};
        float denA = 0.f, denB = 0.f;
        if (lo < hi) {
            // edges i,i+1 resident; xl resident for i+2,i+3; meta for i+4,i+5.
            // in-loop: xl for i+4, meta for i+6. Overruns land in pads.
            int sA = esrc[lo],      sB = esrc[lo + 1];
            uint4 eA = ea8[lo],     eB = ea8[lo + 1];
            int snA = esrc[lo + 2], snB = esrc[lo + 3];
            uint4 enA = ea8[lo + 2], enB = ea8[lo + 3];
            int s2A = esrc[lo + 4], s2B = esrc[lo + 5];
            uint4 e2A = ea8[lo + 4], e2B = ea8[lo + 5];
            uint2 xA = *(const uint2*)(xl + (sA << 7) + c0);
            uint2 xB = *(const uint2*)(xl + (sB << 7) + c0);
            uint2 xnA = *(const uint2*)(xl + (snA << 7) + c0);
            uint2 xnB = *(const uint2*)(xl + (snB << 7) + c0);
            for (int i = lo; i < hi; i += 2) {
                uint2 x2A = *(const uint2*)(xl + (s2A << 7) + c0);  // xl for i+4/i+5
                uint2 x2B = *(const uint2*)(xl + (s2B << 7) + c0);
                int s3A = esrc[i + 6],  s3B = esrc[i + 7];           // meta for i+6/i+7
                uint4 e3A = ea8[i + 6], e3B = ea8[i + 7];
                edge_body(eA, xA, wp, base, at2, 1.f, accA, denA);
                float mB = (i + 1 < hi) ? 1.f : 0.f;
                edge_body(eB, xB, wp, base, at2, mB, accB, denB);
                eA = enA; enA = e2A; e2A = e3A;
                eB = enB; enB = e2B; e2B = e3B;
                xA = xnA; xnA = x2A;
                xB = xnB; xnB = x2B;
                s2A = s3A; s2B = s3B;
            }
            accA[0] += accB[0];
            accA[1] += accB[1];
            denA += denB;
        }
        float inv = (denA > 0.f) ? 1.0f / denA : 0.f;
        uint2 zu = *(const uint2*)(zb + (n << 7) + c0);
        float zv[4];
        zv[0] = __uint_as_float(zu.x << 16);
        zv[1] = __uint_as_float(zu.x & 0xffff0000u);
        zv[2] = __uint_as_float(zu.y << 16);
        zv[3] = __uint_as_float(zu.y & 0xffff0000u);
        float accf[4] = {accA[0].x, accA[0].y, accA[1].x, accA[1].y};
        float4 bo4 = *(const float4*)(P + 256 + c0);
        float v[4];
        float s = 0.f;
        {
            float bov[4] = {bo4.x, bo4.y, bo4.z, bo4.w};
            #pragma unroll
            for (int j = 0; j < 4; j++) {
                float hv = fmaxf(accf[j] * inv + bov[j], 0.f);
                v[j] = zv[j] + hv;
                s += v[j];
            }
        }
        #pragma unroll
        for (int m = 16; m; m >>= 1) s += __shfl_xor(s, m);  // 32-lane sum
        float mu = s * (1.f / HIDD);
        float s2v = 0.f;
        float dv[4];
        #pragma unroll
        for (int j = 0; j < 4; j++) { dv[j] = v[j] - mu; s2v += dv[j] * dv[j]; }
        #pragma unroll
        for (int m = 16; m; m >>= 1) s2v += __shfl_xor(s2v, m);
        float rs = rsqrtf(s2v * (1.f / HIDD) + 1e-5f);
        float4 g4 = *(const float4*)(P + 384 + c0);
        float4 bt4 = *(const float4*)(P + 512 + c0);
        float o[4];
        o[0] = dv[0] * rs * g4.x + bt4.x;
        o[1] = dv[1] * rs * g4.y + bt4.y;
        o[2] = dv[2] * rs * g4.z + bt4.z;
        o[3] = dv[3] * rs * g4.w + bt4.w;
        if constexpr (!LAST) {
            uint2 pk;
            pk.x = (unsigned int)f2bu(o[0]) | ((unsigned int)f2bu(o[1]) << 16);
            pk.y = (unsigned int)f2bu(o[2]) | ((unsigned int)f2bu(o[3]) << 16);
            *(uint2*)(zb + (n << 7) + c0) = pk;
        } else {
            float4 wo4 = *(const float4*)(P + 640 + c0);
            float po = o[0] * wo4.x + o[1] * wo4.y + o[2] * wo4.z + o[3] * wo4.w;
            #pragma unroll
            for (int m = 16; m; m >>= 1) po += __shfl_xor(po, m);
            if (lane5 == 0) {
                float r = po + P[768];
                if (f32out) ((float*)out)[n] = r;
                else        ((bf16*)out)[n] = __float2bfloat16(r);
            }
        }
    }
}
__global__ void k_gat(const int* perm, const int* off, const int* esrc,
                      const uint4* ea8, const unsigned int* wep, const float* prm,
                      const bf16* xl, const bf16* xr, bf16* zb) {
    gat_impl<false>(perm, off, esrc, ea8, wep, prm, xl, xr, zb, nullptr, false);
}
__global__ void k_gat_last(const int* cnt, const int* perm, const int* off, const int* esrc,
                           const uint4* ea8, const unsigned int* wep, const float* prm,
                           const bf16* xl, const bf16* xr, bf16* zb, void* out) {
    gat_impl<true>(perm, off, esrc, ea8, wep, prm, xl, xr, zb, out, is_f32(cnt));
}

extern "C" void kernel_launch(void* const* d_in, const int* in_sizes, int n_in,
                              void* d_out, int out_size, void* d_ws, size_t ws_size,
                              hipStream_t stream) {
    const void* x        = d_in[0];
    const int*  node_idx = (const int*)d_in[1];
    const int*  ei       = (const int*)d_in[2];
    const void* ea       = d_in[3];
    const void* emb      = d_in[4];
    const void* W_in     = d_in[5];
    const void* b_in     = d_in[6];
    const void* Wl1 = d_in[7];  const void* bl1 = d_in[8];
    const void* Wr1 = d_in[9];  const void* br1 = d_in[10];
    const void* We1 = d_in[11]; const void* be1 = d_in[12];
    const void* att1 = d_in[13]; const void* bo1 = d_in[14];
    const void* Wl2 = d_in[15]; const void* bl2 = d_in[16];
    const void* Wr2 = d_in[17]; const void* br2 = d_in[18];
    const void* We2 = d_in[19]; const void* be2 = d_in[20];
    const void* att2 = d_in[21]; const void* bo2 = d_in[22];
    const void* g1 = d_in[23]; const void* beta1 = d_in[24];
    const void* g2 = d_in[25]; const void* beta2 = d_in[26];
    const void* W_out = d_in[27]; const void* b_out = d_in[28];

    // workspace (~55 MB), 16B-aligned sections:
    int*   cnt   = (int*)d_ws;                             // 64 ints
    uint4* ea8   = (uint4*)((char*)d_ws + 256);            // NE+16 (pad slots at NE..)
    bf16*  zb    = (bf16*)(ea8 + NE + 16);                 // NN*HIDD
    bf16*  xl    = zb + NN * HIDD;                         // NN*HIDD
    bf16*  xr    = xl + NN * HIDD;                         // NN*HIDD
    bf16*  wbT   = xr + NN * HIDD;                         // 2*256*128
    float* bias  = (float*)(wbT + 2 * 256 * HIDD);         // 512
    unsigned int* wep = (unsigned int*)(bias + 512);       // 2*512
    float* prm   = (float*)(wep + 1024);                   // 2*PRMF
    int*   off0  = (int*)(prm + 2 * PRMF);                 // NN+1 (partial scan)
    int*   offF  = off0 + NN + 1;                          // NN+1 (final CSR offsets)
    int*   deg   = offF + NN + 1;                          // NN
    int*   rank  = deg + NN;                               // NE
    int*   rankd = rank + NE;                              // NN
    int*   perm  = rankd + NN;                             // NN
    int*   esrc  = perm + NN;                              // NE+16 (pads at NE..)
    int*   bsum  = esrc + NE + 16;                         // 256
    int*   dcnt  = bsum + 256;                             // 80 (ticket at [64])
    int*   dbase = dcnt + 80;                              // 64

    int nhalf = in_sizes[0] < 16384 ? in_sizes[0] : 16384;
    k_detinit<<<NB_SCAN + 1, 256, 0, stream>>>((const unsigned short*)x, nhalf, cnt, deg, dcnt);
    k_hist<<<FILLB, 256, 0, stream>>>(ei, deg, rank);
    k_scan12<<<NB_SCAN, 256, 0, stream>>>(deg, off0, bsum, dcnt, dbase, rankd);
    k_prep<<<NB_SCAN + FILLB + BZB + WPB + 2, 256, 0, stream>>>(
        cnt, off0, bsum, deg, rankd, dbase, perm, offF, ei, rank, esrc, ea8, ea,
        x, node_idx, emb, W_in, b_in, zb,
        Wl1, bl1, Wr1, br1, Wl2, bl2, Wr2, br2, wbT, bias,
        We1, att1, be1, bo1, g1, beta1,
        We2, att2, be2, bo2, g2, beta2,
        W_out, b_out, wep, prm);

    int gatb = (NN + 8 * NPG - 1) / (8 * NPG);  // 1563
    // ---- layer 1 ----
    k_projmm<<<(NN + 63) / 64, 256, 0, stream>>>(zb, wbT, bias, xl, xr);
    k_gat<<<gatb, 256, 0, stream>>>(perm, offF, esrc, ea8, wep, prm, xl, xr, zb);

    // ---- layer 2 ----
    k_projmm<<<(NN + 63) / 64, 256, 0, stream>>>(zb, wbT + 256 * HIDD, bias + 256, xl, xr);
    k_gat_last<<<gatb, 256, 0, stream>>>(cnt, perm, offF, esrc, ea8, wep + 512, prm + PRMF,
                                         xl, xr, zb, d_out);
}

// Round 8
// 356.249 us; speedup vs baseline: 1.0309x; 1.0309x over previous
//
#include <hip/hip_runtime.h>
#include <hip/hip_bf16.h>

#define NN 50000
#define NE 600000
#define IND 16
#define EDD 8
#define HIDD 128
#define NH 4
#define CC 32
#define EMBD 64
#define FEATD 64
#define NB_SCAN ((NN + 255) / 256)  // 196
#define FILLB ((NE + 255) / 256)    // 2344
#define BZB (NN / 16)               // 3125
#define WPB 256
#define PRMF 896                     // per-layer float param stride

typedef __hip_bfloat16 bf16;
typedef __attribute__((ext_vector_type(8))) short bshort8;
typedef __attribute__((ext_vector_type(4))) float floatx4;
typedef __attribute__((ext_vector_type(2))) float f32x2;

// round-to-nearest-even f32 -> bf16 bits
__device__ __forceinline__ unsigned short f2bu(float f) {
    unsigned int u = __float_as_uint(f);
    u += 0x7fffu + ((u >> 16) & 1u);
    return (unsigned short)(u >> 16);
}

// packed bf16x2 dot product with f32 accumulator: a0*b0 + a1*b1 + c
#if defined(__has_builtin)
#if __has_builtin(__builtin_amdgcn_fdot2_f32_bf16)
#define HAS_DOT2BF 1
#endif
#endif
#ifndef HAS_DOT2BF
#define HAS_DOT2BF 0
#endif

#if HAS_DOT2BF
typedef __attribute__((ext_vector_type(2))) __bf16 bfx2;
__device__ __forceinline__ float dot2bf(unsigned int a, unsigned int b, float c) {
    return __builtin_amdgcn_fdot2_f32_bf16(__builtin_bit_cast(bfx2, a),
                                           __builtin_bit_cast(bfx2, b), c, false);
}
#else
__device__ __forceinline__ float dot2bf(unsigned int a, unsigned int b, float c) {
    float a0 = __uint_as_float(a << 16), a1 = __uint_as_float(a & 0xffff0000u);
    float b0 = __uint_as_float(b << 16), b1 = __uint_as_float(b & 0xffff0000u);
    return __builtin_fmaf(a1, b1, __builtin_fmaf(a0, b0, c));
}
#endif

template <bool F32>
__device__ __forceinline__ float LD(const void* p, long long i) {
    if constexpr (F32) return ((const float*)p)[i];
    else return __bfloat162float(((const bf16*)p)[i]);
}

__device__ __forceinline__ bool is_f32(const int* cnt) { return *cnt > 8; }

// ---- CSR histogram (records each edge's rank within its dst bucket).
// Extra block (blockIdx == FILLB) does the dtype detect — hides under the
// 2344 histogram blocks instead of serializing its own launch.
__global__ void k_hist(const unsigned short* __restrict__ x, int nhalf,
                       int* __restrict__ cnt, const int* __restrict__ ei,
                       int* __restrict__ deg, int* __restrict__ rank) {
    if (blockIdx.x == FILLB) {
        __shared__ int red[256];
        int hits = 0;
        for (int i = threadIdx.x; i < nhalf; i += 256)
            if ((x[i] & 0x7F80u) == 0x7F80u) hits++;
        red[threadIdx.x] = hits;
        __syncthreads();
        for (int o = 128; o; o >>= 1) {
            if (threadIdx.x < o) red[threadIdx.x] += red[threadIdx.x + o];
            __syncthreads();
        }
        if (threadIdx.x == 0) *cnt = red[0];
        return;
    }
    int e = blockIdx.x * blockDim.x + threadIdx.x;
    if (e < NE) rank[e] = atomicAdd(&deg[ei[NE + e]], 1);
}

// Degree buckets REVERSED (b = 63 - min(deg,63)): longest blocks dispatch first.
// FUSED scan level 1 + level 2 (last-block-ticket). Cross-block-communicated
// values (bsum) use atomicExch/atomicAdd(p,0) for device-coherent access
// (per-XCD L2s are not coherent for plain load/store).
__global__ void k_scan12(const int* __restrict__ deg, int* __restrict__ off0,
                         int* __restrict__ bsum, int* __restrict__ dcnt,
                         int* __restrict__ dbase, int* __restrict__ rankd) {
    __shared__ int tile[256];
    __shared__ int lh[64];
    __shared__ int lbase[64];
    __shared__ int d2[64];
    __shared__ int ticket;
    int t = threadIdx.x;
    int gid = blockIdx.x * 256 + t;
    if (t < 64) lh[t] = 0;
    __syncthreads();
    int v = (gid < NN) ? deg[gid] : 0;
    int b = 63 - min(v, 63);
    int lr = 0;
    if (gid < NN) lr = atomicAdd(&lh[b], 1);
    tile[t] = v;
    __syncthreads();
    if (t < 64) lbase[t] = lh[t] ? atomicAdd(&dcnt[t], lh[t]) : 0;
    #pragma unroll
    for (int o = 1; o < 256; o <<= 1) {
        int u = (t >= o) ? tile[t - o] : 0;
        __syncthreads();
        tile[t] += u;
        __syncthreads();
    }
    if (gid < NN) {
        off0[gid] = tile[t] - v;
        rankd[gid] = lbase[b] + lr;
    }
    if (t == 255) atomicExch(&bsum[blockIdx.x], tile[255]);  // coherent publish
    __syncthreads();
    if (t == 0) ticket = atomicAdd(&dcnt[64], 1);
    __syncthreads();
    if (ticket != NB_SCAN - 1) return;
    // last block: scan bsum (196) and dcnt (64) exclusively
    int v2 = (t < NB_SCAN) ? atomicAdd(&bsum[t], 0) : 0;    // coherent read
    int dv = (t < 64) ? atomicAdd(&dcnt[t], 0) : 0;
    tile[t] = v2;
    if (t < 64) d2[t] = dv;
    __syncthreads();
    #pragma unroll
    for (int o = 1; o < 256; o <<= 1) {
        int u = (t >= o) ? tile[t - o] : 0;
        __syncthreads();
        tile[t] += u;
        __syncthreads();
    }
    #pragma unroll
    for (int o = 1; o < 64; o <<= 1) {
        int u = (t >= o && t < 64) ? d2[t - o] : 0;
        __syncthreads();
        if (t < 64) d2[t] += u;
        __syncthreads();
    }
    if (t < NB_SCAN) bsum[t] = tile[t] - v2;   // consumed after launch boundary (k_prep)
    if (t < 64) dbase[t] = d2[t] - dv;
}

// ---- MERGED prep kernel (one launch):
//  blocks [0, NB_SCAN)                    : scan3 — offF = off0+bsum, perm scatter
//  blocks [NB_SCAN, +FILLB)               : fill — CSR scatter of esrc/ea8
//  blocks [.., +BZB)                      : build_z, 16 nodes/block
//  blocks [.., +WPB)                      : wbT/bias transpose prep (2 halves/block)
//  last 2 blocks                          : packed GAT params (wep/prm), 1/layer
template <bool F32>
__device__ void prep_impl(const int* __restrict__ off0, const int* __restrict__ bsum,
                          const int* __restrict__ deg, const int* __restrict__ rankd,
                          const int* __restrict__ dbase, int* __restrict__ perm,
                          int* __restrict__ offF,
                          const int* __restrict__ ei, const int* __restrict__ rank,
                          int* __restrict__ esrc, uint4* __restrict__ ea8, const void* ea,
                          const void* x, const int* __restrict__ node_idx, const void* emb,
                          const void* W_in, const void* b_in, bf16* __restrict__ zb,
                          const void* Wl1, const void* bl1, const void* Wr1, const void* br1,
                          const void* Wl2, const void* bl2, const void* Wr2, const void* br2,
                          bf16* __restrict__ wbT, float* __restrict__ bias,
                          const void* We1, const void* att1, const void* be1, const void* bo1,
                          const void* g1, const void* beta1,
                          const void* We2, const void* att2, const void* be2, const void* bo2,
                          const void* g2, const void* beta2,
                          const void* Wo, const void* bout,
                          unsigned int* __restrict__ wep, float* __restrict__ prm) {
    int b = blockIdx.x;
    int t = threadIdx.x;
    if (b < NB_SCAN) {
        int gid = b * 256 + t;
        if (gid < NN) {
            offF[gid] = off0[gid] + bsum[b];
            int bk = 63 - min(deg[gid], 63);
            perm[dbase[bk] + rankd[gid]] = gid;
        }
        if (gid == 0) offF[NN] = NE;
    } else if (b < NB_SCAN + FILLB) {
        int e = (b - NB_SCAN) * 256 + t;
        if (e >= NE) return;
        if (e < 16) {
            esrc[NE + e] = 0;
            uint4 z; z.x = 0; z.y = 0; z.z = 0; z.w = 0;
            ea8[NE + e] = z;
        }
        int dst = ei[NE + e];
        int slot = off0[dst] + bsum[dst >> 8] + rank[e];
        esrc[slot] = ei[e];
        uint4 v;
        if constexpr (F32) {
            const float4* ef = (const float4*)ea;
            float4 f0 = ef[2 * e], f1 = ef[2 * e + 1];
            v.x = (unsigned int)f2bu(f0.x) | ((unsigned int)f2bu(f0.y) << 16);
            v.y = (unsigned int)f2bu(f0.z) | ((unsigned int)f2bu(f0.w) << 16);
            v.z = (unsigned int)f2bu(f1.x) | ((unsigned int)f2bu(f1.y) << 16);
            v.w = (unsigned int)f2bu(f1.z) | ((unsigned int)f2bu(f1.w) << 16);
        } else {
            v = ((const uint4*)ea)[e];  // bf16 pairs already packed
        }
        ea8[slot] = v;
    } else if (b < NB_SCAN + FILLB + BZB) {
        int nb = (b - NB_SCAN - FILLB) * 16 + (t >> 7) * 8;
        int t7 = t & 127;
        if (t7 < FEATD) {  // input projection, weights hoisted to regs
            float w[IND];
            #pragma unroll
            for (int k = 0; k < IND; k++) w[k] = LD<F32>(W_in, k * FEATD + t7);
            float bi = LD<F32>(b_in, t7);
            #pragma unroll 2
            for (int nd = 0; nd < 8; nd++) {
                int n = nb + nd;
                float acc = bi;
                #pragma unroll
                for (int k = 0; k < IND; k++)
                    acc += LD<F32>(x, (long long)n * IND + k) * w[k];
                zb[n * HIDD + t7] = __float2bfloat16(fmaxf(acc, 0.f));
            }
        } else {          // station-embedding gather
            #pragma unroll 2
            for (int nd = 0; nd < 8; nd++) {
                int n = nb + nd;
                zb[n * HIDD + t7] = __float2bfloat16(
                    LD<F32>(emb, (long long)node_idx[n] * EMBD + (t7 - FEATD)));
            }
        }
    } else if (b < NB_SCAN + FILLB + BZB + WPB) {
        int bid2 = (b - NB_SCAN - FILLB - BZB) * 2 + (t >> 7);
        int layer = bid2 >> 8;
        int n2 = bid2 & 255;
        int t7 = t & 127;
        const void* W = layer ? (n2 < HIDD ? Wl2 : Wr2) : (n2 < HIDD ? Wl1 : Wr1);
        const void* bb = layer ? (n2 < HIDD ? bl2 : br2) : (n2 < HIDD ? bl1 : br1);
        int nn = n2 & (HIDD - 1);
        wbT[(layer * 256 + n2) * HIDD + t7] = __float2bfloat16(LD<F32>(W, t7 * HIDD + nn));
        if (t7 == 0) bias[layer * 256 + n2] = LD<F32>(bb, nn);
    } else {
        int layer = b - (NB_SCAN + FILLB + BZB + WPB);
        const void* We = layer ? We2 : We1;
        const void* att = layer ? att2 : att1;
        const void* be = layer ? be2 : be1;
        const void* bo = layer ? bo2 : bo1;
        const void* g  = layer ? g2 : g1;
        const void* bt = layer ? beta2 : beta1;
        if (t < 128) {
            // wep[layer][lane5*16 + p*4 + j] = pack(We[2p][c0+j], We[2p+1][c0+j])
            int lane5 = t >> 2, j = t & 3, c0 = lane5 * 4;
            #pragma unroll
            for (int p = 0; p < 4; p++) {
                unsigned int lo_ = f2bu(LD<F32>(We, (2 * p) * HIDD + c0 + j));
                unsigned int hi_ = f2bu(LD<F32>(We, (2 * p + 1) * HIDD + c0 + j));
                wep[layer * 512 + lane5 * 16 + p * 4 + j] = lo_ | (hi_ << 16);
            }
        } else {
            int t2 = t - 128;
            float* Pp = prm + layer * PRMF;
            Pp[t2]        = LD<F32>(att, t2) * 1.4426950408889634f;  // att*log2e
            Pp[128 + t2]  = LD<F32>(be, t2);
            Pp[256 + t2]  = LD<F32>(bo, t2);
            Pp[384 + t2]  = LD<F32>(g, t2);
            Pp[512 + t2]  = LD<F32>(bt, t2);
            if (layer) {
                Pp[640 + t2] = LD<F32>(Wo, t2);
                if (t2 == 0) Pp[768] = LD<F32>(bout, 0);
            }
        }
    }
}
__global__ void k_prep(const int* cnt, const int* off0, const int* bsum, const int* deg,
                       const int* rankd, const int* dbase, int* perm, int* offF,
                       const int* ei, const int* rank, int* esrc, uint4* ea8, const void* ea,
                       const void* x, const int* node_idx, const void* emb,
                       const void* W_in, const void* b_in, bf16* zb,
                       const void* Wl1, const void* bl1, const void* Wr1, const void* br1,
                       const void* Wl2, const void* bl2, const void* Wr2, const void* br2,
                       bf16* wbT, float* bias,
                       const void* We1, const void* att1, const void* be1, const void* bo1,
                       const void* g1, const void* beta1,
                       const void* We2, const void* att2, const void* be2, const void* bo2,
                       const void* g2, const void* beta2,
                       const void* Wo, const void* bout,
                       unsigned int* wep, float* prm) {
    if (is_f32(cnt))
        prep_impl<true>(off0, bsum, deg, rankd, dbase, perm, offF, ei, rank, esrc, ea8, ea,
                        x, node_idx, emb, W_in, b_in, zb, Wl1, bl1, Wr1, br1,
                        Wl2, bl2, Wr2, br2, wbT, bias, We1, att1, be1, bo1, g1, beta1,
                        We2, att2, be2, bo2, g2, beta2, Wo, bout, wep, prm);
    else
        prep_impl<false>(off0, bsum, deg, rankd, dbase, perm, offF, ei, rank, esrc, ea8, ea,
                         x, node_idx, emb, W_in, b_in, zb, Wl1, bl1, Wr1, br1,
                         Wl2, bl2, Wr2, br2, wbT, bias, We1, att1, be1, bo1, g1, beta1,
                         We2, att2, be2, bo2, g2, beta2, Wo, bout, wep, prm);
}

// ---- MFMA projection, SWAPPED operands: D[channel][node] = W·zb^T.
// Each lane holds 4 CONSECUTIVE channels of one node -> single 8B store.
// 64 nodes per block (4 node-tiles), weight fragments loaded once per wave.
__global__ __launch_bounds__(256) void k_projmm(const bf16* __restrict__ zb,
                                                const bf16* __restrict__ wbT,
                                                const float* __restrict__ bias,
                                                bf16* __restrict__ xl, bf16* __restrict__ xr) {
    int wave = threadIdx.x >> 6, lane = threadIdx.x & 63;
    int n0 = wave * 64;             // output-channel base (0..255)
    int l15 = lane & 15, q = lane >> 4;
    bshort8 afr[4][4];  // [j][s]: A rows = channels n0+j*16+l15, k-slice s*32+q*8
    #pragma unroll
    for (int j = 0; j < 4; j++)
        #pragma unroll
        for (int s = 0; s < 4; s++)
            afr[j][s] = *(const bshort8*)(wbT + ((n0 + j * 16 + l15) << 7) + s * 32 + q * 8);
    float4 bias4[4];
    #pragma unroll
    for (int j = 0; j < 4; j++) bias4[j] = *(const float4*)(bias + n0 + j * 16 + q * 4);
    bf16* dst = (n0 < HIDD) ? xl : xr;
    int cbase = (n0 & (HIDD - 1)) + q * 4;
    int nodeBase = blockIdx.x * 64;
    #pragma unroll
    for (int mt = 0; mt < 4; mt++) {
        int node = nodeBase + mt * 16 + l15;
        const bf16* brow = zb + (node << 7) + q * 8;  // OOB rows read into xl region (safe)
        bshort8 bfrag[4];
        #pragma unroll
        for (int s = 0; s < 4; s++) bfrag[s] = *(const bshort8*)(brow + s * 32);
        floatx4 acc0 = {0.f, 0.f, 0.f, 0.f}, acc1 = acc0, acc2 = acc0, acc3 = acc0;
        #pragma unroll
        for (int s = 0; s < 4; s++) {
            acc0 = __builtin_amdgcn_mfma_f32_16x16x32_bf16(afr[0][s], bfrag[s], acc0, 0, 0, 0);
            acc1 = __builtin_amdgcn_mfma_f32_16x16x32_bf16(afr[1][s], bfrag[s], acc1, 0, 0, 0);
            acc2 = __builtin_amdgcn_mfma_f32_16x16x32_bf16(afr[2][s], bfrag[s], acc2, 0, 0, 0);
            acc3 = __builtin_amdgcn_mfma_f32_16x16x32_bf16(afr[3][s], bfrag[s], acc3, 0, 0, 0);
        }
        if (node < NN) {
            floatx4 accs[4] = {acc0, acc1, acc2, acc3};
            #pragma unroll
            for (int j = 0; j < 4; j++) {
                float4 bv = bias4[j];
                uint2 pk;
                pk.x = (unsigned int)f2bu(accs[j][0] + bv.x) |
                       ((unsigned int)f2bu(accs[j][1] + bv.y) << 16);
                pk.y = (unsigned int)f2bu(accs[j][2] + bv.z) |
                       ((unsigned int)f2bu(accs[j][3] + bv.w) << 16);
                *(uint2*)(dst + (node << 7) + cbase + j * 16) = pk;
            }
        }
    }
}

// ---- per-edge compute body (half-wave: 32 lanes, 4 ch/lane, 8-lane head groups)
__device__ __forceinline__ void edge_body(uint4 eu, uint2 xu, const unsigned int (*wp)[4],
                                          const float* base, const f32x2* at2,
                                          float mask, f32x2* acc, float& den) {
    f32x2 xv0, xv1;
    xv0.x = __uint_as_float(xu.x << 16); xv0.y = __uint_as_float(xu.x & 0xffff0000u);
    xv1.x = __uint_as_float(xu.y << 16); xv1.y = __uint_as_float(xu.y & 0xffff0000u);
    f32x2 e01, e23;
    {
        float c0 = base[0];
        c0 = dot2bf(eu.x, wp[0][0], c0);
        c0 = dot2bf(eu.y, wp[1][0], c0);
        c0 = dot2bf(eu.z, wp[2][0], c0);
        c0 = dot2bf(eu.w, wp[3][0], c0);
        float c1 = base[1];
        c1 = dot2bf(eu.x, wp[0][1], c1);
        c1 = dot2bf(eu.y, wp[1][1], c1);
        c1 = dot2bf(eu.z, wp[2][1], c1);
        c1 = dot2bf(eu.w, wp[3][1], c1);
        e01.x = c0; e01.y = c1;
        float c2 = base[2];
        c2 = dot2bf(eu.x, wp[0][2], c2);
        c2 = dot2bf(eu.y, wp[1][2], c2);
        c2 = dot2bf(eu.z, wp[2][2], c2);
        c2 = dot2bf(eu.w, wp[3][2], c2);
        float c3 = base[3];
        c3 = dot2bf(eu.x, wp[0][3], c3);
        c3 = dot2bf(eu.y, wp[1][3], c3);
        c3 = dot2bf(eu.z, wp[2][3], c3);
        c3 = dot2bf(eu.w, wp[3][3], c3);
        e23.x = c2; e23.y = c3;
    }
    f32x2 s0 = xv0 + e01;
    f32x2 s1 = xv1 + e23;
    s0 = __builtin_elementwise_max(s0, s0 * 0.2f);  // leakyrelu (packed)
    s1 = __builtin_elementwise_max(s1, s1 * 0.2f);
    f32x2 lsv = s0 * at2[0] + s1 * at2[1];
    float ls = lsv.x + lsv.y;
    ls += __shfl_xor(ls, 1);
    ls += __shfl_xor(ls, 2);
    ls += __shfl_xor(ls, 4);   // 8-lane head group = 32 channels
    float ex = exp2f(ls) * mask;  // att pre-scaled by log2e
    acc[0] += ex * xv0;
    acc[1] += ex * xv1;
    den += ex;
}

// ---- fused GAT layer: 2 nodes per wave (degree-matched via global-sort perm),
// 4 ch/lane, 2-edge ILP with three-level rotating prefetch (xl TWO iters ahead,
// esrc/ea8 three iters ahead; pad slots NE..NE+15), barrier-free LN.
// All per-layer params pre-packed (wep: bf16-pair edge weights; P: f32 vectors).
// LAST fuses the output head. [NPG=4 regressed (r7: occ 46->31%); keep 1.]
template <bool LAST>
__device__ __forceinline__ void gat_impl(const int* __restrict__ perm,
                         const int* __restrict__ off, const int* __restrict__ esrc,
                         const uint4* __restrict__ ea8,
                         const unsigned int* __restrict__ wep,
                         const float* __restrict__ P,
                         const bf16* __restrict__ xl, const bf16* __restrict__ xr,
                         bf16* __restrict__ zb, void* out, bool f32out) {
    int wave = threadIdx.x >> 6;
    int half = (threadIdx.x >> 5) & 1;
    int lane5 = threadIdx.x & 31;
    int n = perm[blockIdx.x * 8 + wave * 2 + half];
    int c0 = lane5 << 2;  // 4 channels c0..c0+3 ; head = lane5>>3
    unsigned int wp[4][4];
    {
        const uint4* w4 = (const uint4*)(wep + lane5 * 16);
        uint4 wa = w4[0], wb = w4[1], wc = w4[2], wd = w4[3];
        wp[0][0] = wa.x; wp[0][1] = wa.y; wp[0][2] = wa.z; wp[0][3] = wa.w;
        wp[1][0] = wb.x; wp[1][1] = wb.y; wp[1][2] = wb.z; wp[1][3] = wb.w;
        wp[2][0] = wc.x; wp[2][1] = wc.y; wp[2][2] = wc.z; wp[2][3] = wc.w;
        wp[3][0] = wd.x; wp[3][1] = wd.y; wp[3][2] = wd.z; wp[3][3] = wd.w;
    }
    float4 atv = *(const float4*)(P + c0);
    f32x2 at2[2];
    at2[0].x = atv.x; at2[0].y = atv.y;
    at2[1].x = atv.z; at2[1].y = atv.w;
    float4 bev = *(const float4*)(P + 128 + c0);
    uint2 xru = *(const uint2*)(xr + (n << 7) + c0);
    float base[4];
    base[0] = bev.x + __uint_as_float(xru.x << 16);
    base[1] = bev.y + __uint_as_float(xru.x & 0xffff0000u);
    base[2] = bev.z + __uint_as_float(xru.y << 16);
    base[3] = bev.w + __uint_as_float(xru.y & 0xffff0000u);
    int lo = off[n], hi = off[n + 1];
    f32x2 accA[2] = {{0.f, 0.f}, {0.f, 0.f}}, accB[2] = {{0.f, 0.f}, {0.f, 0.f}};
    float denA = 0.f, denB = 0.f;
    if (lo < hi) {
        // pipeline: edges i,i+1 fully resident; xl resident for i+2,i+3;
        // meta (esrc/ea8) resident for i+4,i+5. In-loop: issue xl for i+4,
        // meta for i+6. All overruns land in pad slots NE..NE+15.
        int sA = esrc[lo],      sB = esrc[lo + 1];
        uint4 eA = ea8[lo],     eB = ea8[lo + 1];
        int snA = esrc[lo + 2], snB = esrc[lo + 3];
        uint4 enA = ea8[lo + 2], enB = ea8[lo + 3];
        int s2A = esrc[lo + 4], s2B = esrc[lo + 5];
        uint4 e2A = ea8[lo + 4], e2B = ea8[lo + 5];
        uint2 xA = *(const uint2*)(xl + (sA << 7) + c0);
        uint2 xB = *(const uint2*)(xl + (sB << 7) + c0);
        uint2 xnA = *(const uint2*)(xl + (snA << 7) + c0);
        uint2 xnB = *(const uint2*)(xl + (snB << 7) + c0);
        for (int i = lo; i < hi; i += 2) {
            uint2 x2A = *(const uint2*)(xl + (s2A << 7) + c0);  // xl for i+4/i+5
            uint2 x2B = *(const uint2*)(xl + (s2B << 7) + c0);
            int s3A = esrc[i + 6],  s3B = esrc[i + 7];           // meta for i+6/i+7
            uint4 e3A = ea8[i + 6], e3B = ea8[i + 7];
            edge_body(eA, xA, wp, base, at2, 1.f, accA, denA);
            float mB = (i + 1 < hi) ? 1.f : 0.f;
            edge_body(eB, xB, wp, base, at2, mB, accB, denB);
            eA = enA; enA = e2A; e2A = e3A;
            eB = enB; enB = e2B; e2B = e3B;
            xA = xnA; xnA = x2A;
            xB = xnB; xnB = x2B;
            s2A = s3A; s2B = s3B;
        }
        accA[0] += accB[0];
        accA[1] += accB[1];
        denA += denB;
    }
    float inv = (denA > 0.f) ? 1.0f / denA : 0.f;
    uint2 zu = *(const uint2*)(zb + (n << 7) + c0);
    float zv[4];
    zv[0] = __uint_as_float(zu.x << 16);
    zv[1] = __uint_as_float(zu.x & 0xffff0000u);
    zv[2] = __uint_as_float(zu.y << 16);
    zv[3] = __uint_as_float(zu.y & 0xffff0000u);
    float accf[4] = {accA[0].x, accA[0].y, accA[1].x, accA[1].y};
    float4 bo4 = *(const float4*)(P + 256 + c0);
    float bov[4] = {bo4.x, bo4.y, bo4.z, bo4.w};
    float v[4];
    float s = 0.f;
    #pragma unroll
    for (int j = 0; j < 4; j++) {
        float hv = fmaxf(accf[j] * inv + bov[j], 0.f);
        v[j] = zv[j] + hv;
        s += v[j];
    }
    #pragma unroll
    for (int m = 16; m; m >>= 1) s += __shfl_xor(s, m);  // 32-lane sum
    float mu = s * (1.f / HIDD);
    float s2v = 0.f;
    float dv[4];
    #pragma unroll
    for (int j = 0; j < 4; j++) { dv[j] = v[j] - mu; s2v += dv[j] * dv[j]; }
    #pragma unroll
    for (int m = 16; m; m >>= 1) s2v += __shfl_xor(s2v, m);
    float rs = rsqrtf(s2v * (1.f / HIDD) + 1e-5f);
    float4 g4 = *(const float4*)(P + 384 + c0);
    float4 bt4 = *(const float4*)(P + 512 + c0);
    float gv[4] = {g4.x, g4.y, g4.z, g4.w};
    float btv[4] = {bt4.x, bt4.y, bt4.z, bt4.w};
    float o[4];
    #pragma unroll
    for (int j = 0; j < 4; j++)
        o[j] = dv[j] * rs * gv[j] + btv[j];
    if constexpr (!LAST) {
        uint2 pk;
        pk.x = (unsigned int)f2bu(o[0]) | ((unsigned int)f2bu(o[1]) << 16);
        pk.y = (unsigned int)f2bu(o[2]) | ((unsigned int)f2bu(o[3]) << 16);
        *(uint2*)(zb + (n << 7) + c0) = pk;
    } else {
        float4 wo4 = *(const float4*)(P + 640 + c0);
        float wov[4] = {wo4.x, wo4.y, wo4.z, wo4.w};
        float po = 0.f;
        #pragma unroll
        for (int j = 0; j < 4; j++) po += o[j] * wov[j];
        #pragma unroll
        for (int m = 16; m; m >>= 1) po += __shfl_xor(po, m);
        if (lane5 == 0) {
            float r = po + P[768];
            if (f32out) ((float*)out)[n] = r;
            else        ((bf16*)out)[n] = __float2bfloat16(r);
        }
    }
}
__global__ void k_gat(const int* perm, const int* off, const int* esrc,
                      const uint4* ea8, const unsigned int* wep, const float* prm,
                      const bf16* xl, const bf16* xr, bf16* zb) {
    gat_impl<false>(perm, off, esrc, ea8, wep, prm, xl, xr, zb, nullptr, false);
}
__global__ void k_gat_last(const int* cnt, const int* perm, const int* off, const int* esrc,
                           const uint4* ea8, const unsigned int* wep, const float* prm,
                           const bf16* xl, const bf16* xr, bf16* zb, void* out) {
    gat_impl<true>(perm, off, esrc, ea8, wep, prm, xl, xr, zb, out, is_f32(cnt));
}

extern "C" void kernel_launch(void* const* d_in, const int* in_sizes, int n_in,
                              void* d_out, int out_size, void* d_ws, size_t ws_size,
                              hipStream_t stream) {
    const void* x        = d_in[0];
    const int*  node_idx = (const int*)d_in[1];
    const int*  ei       = (const int*)d_in[2];
    const void* ea       = d_in[3];
    const void* emb      = d_in[4];
    const void* W_in     = d_in[5];
    const void* b_in     = d_in[6];
    const void* Wl1 = d_in[7];  const void* bl1 = d_in[8];
    const void* Wr1 = d_in[9];  const void* br1 = d_in[10];
    const void* We1 = d_in[11]; const void* be1 = d_in[12];
    const void* att1 = d_in[13]; const void* bo1 = d_in[14];
    const void* Wl2 = d_in[15]; const void* bl2 = d_in[16];
    const void* Wr2 = d_in[17]; const void* br2 = d_in[18];
    const void* We2 = d_in[19]; const void* be2 = d_in[20];
    const void* att2 = d_in[21]; const void* bo2 = d_in[22];
    const void* g1 = d_in[23]; const void* beta1 = d_in[24];
    const void* g2 = d_in[25]; const void* beta2 = d_in[26];
    const void* W_out = d_in[27]; const void* b_out = d_in[28];

    // workspace (~55 MB), 16B-aligned sections:
    int*   cnt   = (int*)d_ws;                             // 64 ints
    uint4* ea8   = (uint4*)((char*)d_ws + 256);            // NE+16 (pad slots at NE..)
    bf16*  zb    = (bf16*)(ea8 + NE + 16);                 // NN*HIDD
    bf16*  xl    = zb + NN * HIDD;                         // NN*HIDD
    bf16*  xr    = xl + NN * HIDD;                         // NN*HIDD
    bf16*  wbT   = xr + NN * HIDD;                         // 2*256*128
    float* bias  = (float*)(wbT + 2 * 256 * HIDD);         // 512
    unsigned int* wep = (unsigned int*)(bias + 512);       // 2*512
    float* prm   = (float*)(wep + 1024);                   // 2*PRMF
    int*   off0  = (int*)(prm + 2 * PRMF);                 // NN+1 (partial scan)
    int*   offF  = off0 + NN + 1;                          // NN+1 (final CSR offsets)
    int*   deg   = offF + NN + 1;                          // NN
    int*   rank  = deg + NN;                               // NE
    int*   rankd = rank + NE;                              // NN
    int*   perm  = rankd + NN;                             // NN
    int*   esrc  = perm + NN;                              // NE+16 (pads at NE..)
    int*   bsum  = esrc + NE + 16;                         // 256
    int*   dcnt  = bsum + 256;                             // 80 (ticket at [64])
    int*   dbase = dcnt + 80;                              // 64

    int nhalf = in_sizes[0] < 16384 ? in_sizes[0] : 16384;
    hipMemsetAsync(deg, 0, NN * sizeof(int), stream);
    hipMemsetAsync(dcnt, 0, 80 * sizeof(int), stream);
    k_hist<<<FILLB + 1, 256, 0, stream>>>((const unsigned short*)x, nhalf, cnt, ei, deg, rank);
    k_scan12<<<NB_SCAN, 256, 0, stream>>>(deg, off0, bsum, dcnt, dbase, rankd);
    k_prep<<<NB_SCAN + FILLB + BZB + WPB + 2, 256, 0, stream>>>(
        cnt, off0, bsum, deg, rankd, dbase, perm, offF, ei, rank, esrc, ea8, ea,
        x, node_idx, emb, W_in, b_in, zb,
        Wl1, bl1, Wr1, br1, Wl2, bl2, Wr2, br2, wbT, bias,
        We1, att1, be1, bo1, g1, beta1,
        We2, att2, be2, bo2, g2, beta2,
        W_out, b_out, wep, prm);

    // ---- layer 1 ----
    k_projmm<<<(NN + 63) / 64, 256, 0, stream>>>(zb, wbT, bias, xl, xr);
    k_gat<<<NN / 8, 256, 0, stream>>>(perm, offF, esrc, ea8, wep, prm, xl, xr, zb);

    // ---- layer 2 ----
    k_projmm<<<(NN + 63) / 64, 256, 0, stream>>>(zb, wbT + 256 * HIDD, bias + 256, xl, xr);
    k_gat_last<<<NN / 8, 256, 0, stream>>>(cnt, perm, offF, esrc, ea8, wep + 512, prm + PRMF,
                                           xl, xr, zb, d_out);
}

// Round 9
// 344.323 us; speedup vs baseline: 1.0666x; 1.0346x over previous
//
#include <hip/hip_runtime.h>
#include <hip/hip_bf16.h>

#define NN 50000
#define NE 600000
#define IND 16
#define EDD 8
#define HIDD 128
#define NH 4
#define CC 32
#define EMBD 64
#define FEATD 64
#define NB_SCAN ((NN + 255) / 256)  // 196
#define FILLB ((NE + 255) / 256)    // 2344
#define BZB (NN / 16)               // 3125
#define WPB 256
#define PJB ((NN + 63) / 64)        // 782 projmm blocks
#define PRMF 896                     // per-layer float param stride

typedef __hip_bfloat16 bf16;
typedef __attribute__((ext_vector_type(8))) short bshort8;
typedef __attribute__((ext_vector_type(4))) float floatx4;
typedef __attribute__((ext_vector_type(2))) float f32x2;

// round-to-nearest-even f32 -> bf16 bits
__device__ __forceinline__ unsigned short f2bu(float f) {
    unsigned int u = __float_as_uint(f);
    u += 0x7fffu + ((u >> 16) & 1u);
    return (unsigned short)(u >> 16);
}

// packed bf16x2 dot product with f32 accumulator: a0*b0 + a1*b1 + c
#if defined(__has_builtin)
#if __has_builtin(__builtin_amdgcn_fdot2_f32_bf16)
#define HAS_DOT2BF 1
#endif
#endif
#ifndef HAS_DOT2BF
#define HAS_DOT2BF 0
#endif

#if HAS_DOT2BF
typedef __attribute__((ext_vector_type(2))) __bf16 bfx2;
__device__ __forceinline__ float dot2bf(unsigned int a, unsigned int b, float c) {
    return __builtin_amdgcn_fdot2_f32_bf16(__builtin_bit_cast(bfx2, a),
                                           __builtin_bit_cast(bfx2, b), c, false);
}
#else
__device__ __forceinline__ float dot2bf(unsigned int a, unsigned int b, float c) {
    float a0 = __uint_as_float(a << 16), a1 = __uint_as_float(a & 0xffff0000u);
    float b0 = __uint_as_float(b << 16), b1 = __uint_as_float(b & 0xffff0000u);
    return __builtin_fmaf(a1, b1, __builtin_fmaf(a0, b0, c));
}
#endif

template <bool F32>
__device__ __forceinline__ float LD(const void* p, long long i) {
    if constexpr (F32) return ((const float*)p)[i];
    else return __bfloat162float(((const bf16*)p)[i]);
}

__device__ __forceinline__ bool is_f32(const int* cnt) { return *cnt > 8; }

// ---- merged: dtype detect (block 0, LDS reduce, no atomics) + zero deg/dcnt/ticket
__global__ void k_detinit(const unsigned short* __restrict__ x, int nhalf,
                          int* __restrict__ cnt, int* __restrict__ deg,
                          int* __restrict__ dcnt) {
    if (blockIdx.x == 0) {
        __shared__ int red[256];
        int hits = 0;
        for (int i = threadIdx.x; i < nhalf; i += 256)
            if ((x[i] & 0x7F80u) == 0x7F80u) hits++;
        red[threadIdx.x] = hits;
        __syncthreads();
        for (int o = 128; o; o >>= 1) {
            if (threadIdx.x < o) red[threadIdx.x] += red[threadIdx.x + o];
            __syncthreads();
        }
        if (threadIdx.x == 0) *cnt = red[0];
    } else {
        int gid = (blockIdx.x - 1) * 256 + threadIdx.x;
        if (gid < NN) deg[gid] = 0;
        if (blockIdx.x == 1 && threadIdx.x < 80) dcnt[threadIdx.x] = 0;  // 64 buckets + ticket
    }
}

// ---- CSR: histogram also records each edge's rank within its dst bucket
__global__ void k_hist(const int* __restrict__ ei, int* __restrict__ deg, int* __restrict__ rank) {
    int e = blockIdx.x * blockDim.x + threadIdx.x;
    if (e < NE) rank[e] = atomicAdd(&deg[ei[NE + e]], 1);
}

// Degree buckets REVERSED (b = 63 - min(deg,63)): longest blocks dispatch first.
// FUSED scan level 1 + level 2 (last-block-ticket). Cross-block-communicated
// values (bsum) use atomicExch/atomicAdd(p,0) for device-coherent access
// (per-XCD L2s are not coherent for plain load/store).
__global__ void k_scan12(const int* __restrict__ deg, int* __restrict__ off0,
                         int* __restrict__ bsum, int* __restrict__ dcnt,
                         int* __restrict__ dbase, int* __restrict__ rankd) {
    __shared__ int tile[256];
    __shared__ int lh[64];
    __shared__ int lbase[64];
    __shared__ int d2[64];
    __shared__ int ticket;
    int t = threadIdx.x;
    int gid = blockIdx.x * 256 + t;
    if (t < 64) lh[t] = 0;
    __syncthreads();
    int v = (gid < NN) ? deg[gid] : 0;
    int b = 63 - min(v, 63);
    int lr = 0;
    if (gid < NN) lr = atomicAdd(&lh[b], 1);
    tile[t] = v;
    __syncthreads();
    if (t < 64) lbase[t] = lh[t] ? atomicAdd(&dcnt[t], lh[t]) : 0;
    #pragma unroll
    for (int o = 1; o < 256; o <<= 1) {
        int u = (t >= o) ? tile[t - o] : 0;
        __syncthreads();
        tile[t] += u;
        __syncthreads();
    }
    if (gid < NN) {
        off0[gid] = tile[t] - v;
        rankd[gid] = lbase[b] + lr;
    }
    if (t == 255) atomicExch(&bsum[blockIdx.x], tile[255]);  // coherent publish
    __syncthreads();
    if (t == 0) ticket = atomicAdd(&dcnt[64], 1);
    __syncthreads();
    if (ticket != NB_SCAN - 1) return;
    // last block: scan bsum (196) and dcnt (64) exclusively
    int v2 = (t < NB_SCAN) ? atomicAdd(&bsum[t], 0) : 0;    // coherent read
    int dv = (t < 64) ? atomicAdd(&dcnt[t], 0) : 0;
    tile[t] = v2;
    if (t < 64) d2[t] = dv;
    __syncthreads();
    #pragma unroll
    for (int o = 1; o < 256; o <<= 1) {
        int u = (t >= o) ? tile[t - o] : 0;
        __syncthreads();
        tile[t] += u;
        __syncthreads();
    }
    #pragma unroll
    for (int o = 1; o < 64; o <<= 1) {
        int u = (t >= o && t < 64) ? d2[t - o] : 0;
        __syncthreads();
        if (t < 64) d2[t] += u;
        __syncthreads();
    }
    if (t < NB_SCAN) bsum[t] = tile[t] - v2;   // consumed after launch boundary (k_prep)
    if (t < 64) dbase[t] = d2[t] - dv;
}

// ---- MERGED prep kernel (one launch):
//  blocks [0, NB_SCAN)        : scan3 — offF = off0+bsum, perm scatter
//  blocks [NB_SCAN, +FILLB)   : fill PHASE 1 — esrc[slot] = e (4B scatter only;
//                               phase 2 transforms in place + gathers ea)
//  blocks [.., +BZB)          : build_z, 16 nodes/block
//  blocks [.., +WPB)          : wbT/bias transpose prep (2 halves/block)
//  last 2 blocks              : packed GAT params (wep/prm), 1/layer
template <bool F32>
__device__ void prep_impl(const int* __restrict__ off0, const int* __restrict__ bsum,
                          const int* __restrict__ deg, const int* __restrict__ rankd,
                          const int* __restrict__ dbase, int* __restrict__ perm,
                          int* __restrict__ offF,
                          const int* __restrict__ ei, const int* __restrict__ rank,
                          int* __restrict__ esrc,
                          const void* x, const int* __restrict__ node_idx, const void* emb,
                          const void* W_in, const void* b_in, bf16* __restrict__ zb,
                          const void* Wl1, const void* bl1, const void* Wr1, const void* br1,
                          const void* Wl2, const void* bl2, const void* Wr2, const void* br2,
                          bf16* __restrict__ wbT, float* __restrict__ bias,
                          const void* We1, const void* att1, const void* be1, const void* bo1,
                          const void* g1, const void* beta1,
                          const void* We2, const void* att2, const void* be2, const void* bo2,
                          const void* g2, const void* beta2,
                          const void* Wo, const void* bout,
                          unsigned int* __restrict__ wep, float* __restrict__ prm) {
    int b = blockIdx.x;
    int t = threadIdx.x;
    if (b < NB_SCAN) {
        int gid = b * 256 + t;
        if (gid < NN) {
            offF[gid] = off0[gid] + bsum[b];
            int bk = 63 - min(deg[gid], 63);
            perm[dbase[bk] + rankd[gid]] = gid;
        }
        if (gid == 0) offF[NN] = NE;
    } else if (b < NB_SCAN + FILLB) {
        int e = (b - NB_SCAN) * 256 + t;
        if (e >= NE) return;
        int dst = ei[NE + e];
        int slot = off0[dst] + bsum[dst >> 8] + rank[e];
        esrc[slot] = e;  // phase 1: edge-id permutation (4B scatter)
    } else if (b < NB_SCAN + FILLB + BZB) {
        int nb = (b - NB_SCAN - FILLB) * 16 + (t >> 7) * 8;
        int t7 = t & 127;
        if (t7 < FEATD) {  // input projection, weights hoisted to regs
            float w[IND];
            #pragma unroll
            for (int k = 0; k < IND; k++) w[k] = LD<F32>(W_in, k * FEATD + t7);
            float bi = LD<F32>(b_in, t7);
            #pragma unroll 2
            for (int nd = 0; nd < 8; nd++) {
                int n = nb + nd;
                float acc = bi;
                #pragma unroll
                for (int k = 0; k < IND; k++)
                    acc += LD<F32>(x, (long long)n * IND + k) * w[k];
                zb[n * HIDD + t7] = __float2bfloat16(fmaxf(acc, 0.f));
            }
        } else {          // station-embedding gather
            #pragma unroll 2
            for (int nd = 0; nd < 8; nd++) {
                int n = nb + nd;
                zb[n * HIDD + t7] = __float2bfloat16(
                    LD<F32>(emb, (long long)node_idx[n] * EMBD + (t7 - FEATD)));
            }
        }
    } else if (b < NB_SCAN + FILLB + BZB + WPB) {
        int bid2 = (b - NB_SCAN - FILLB - BZB) * 2 + (t >> 7);
        int layer = bid2 >> 8;
        int n2 = bid2 & 255;
        int t7 = t & 127;
        const void* W = layer ? (n2 < HIDD ? Wl2 : Wr2) : (n2 < HIDD ? Wl1 : Wr1);
        const void* bb = layer ? (n2 < HIDD ? bl2 : br2) : (n2 < HIDD ? bl1 : br1);
        int nn = n2 & (HIDD - 1);
        wbT[(layer * 256 + n2) * HIDD + t7] = __float2bfloat16(LD<F32>(W, t7 * HIDD + nn));
        if (t7 == 0) bias[layer * 256 + n2] = LD<F32>(bb, nn);
    } else {
        int layer = b - (NB_SCAN + FILLB + BZB + WPB);
        const void* We = layer ? We2 : We1;
        const void* att = layer ? att2 : att1;
        const void* be = layer ? be2 : be1;
        const void* bo = layer ? bo2 : bo1;
        const void* g  = layer ? g2 : g1;
        const void* bt = layer ? beta2 : beta1;
        if (t < 128) {
            // wep[layer][lane5*16 + p*4 + j] = pack(We[2p][c0+j], We[2p+1][c0+j])
            int lane5 = t >> 2, j = t & 3, c0 = lane5 * 4;
            #pragma unroll
            for (int p = 0; p < 4; p++) {
                unsigned int lo_ = f2bu(LD<F32>(We, (2 * p) * HIDD + c0 + j));
                unsigned int hi_ = f2bu(LD<F32>(We, (2 * p + 1) * HIDD + c0 + j));
                wep[layer * 512 + lane5 * 16 + p * 4 + j] = lo_ | (hi_ << 16);
            }
        } else {
            int t2 = t - 128;
            float* Pp = prm + layer * PRMF;
            Pp[t2]        = LD<F32>(att, t2) * 1.4426950408889634f;  // att*log2e
            Pp[128 + t2]  = LD<F32>(be, t2);
            Pp[256 + t2]  = LD<F32>(bo, t2);
            Pp[384 + t2]  = LD<F32>(g, t2);
            Pp[512 + t2]  = LD<F32>(bt, t2);
            if (layer) {
                Pp[640 + t2] = LD<F32>(Wo, t2);
                if (t2 == 0) Pp[768] = LD<F32>(bout, 0);
            }
        }
    }
}
__global__ void k_prep(const int* cnt, const int* off0, const int* bsum, const int* deg,
                       const int* rankd, const int* dbase, int* perm, int* offF,
                       const int* ei, const int* rank, int* esrc,
                       const void* x, const int* node_idx, const void* emb,
                       const void* W_in, const void* b_in, bf16* zb,
                       const void* Wl1, const void* bl1, const void* Wr1, const void* br1,
                       const void* Wl2, const void* bl2, const void* Wr2, const void* br2,
                       bf16* wbT, float* bias,
                       const void* We1, const void* att1, const void* be1, const void* bo1,
                       const void* g1, const void* beta1,
                       const void* We2, const void* att2, const void* be2, const void* bo2,
                       const void* g2, const void* beta2,
                       const void* Wo, const void* bout,
                       unsigned int* wep, float* prm) {
    if (is_f32(cnt))
        prep_impl<true>(off0, bsum, deg, rankd, dbase, perm, offF, ei, rank, esrc,
                        x, node_idx, emb, W_in, b_in, zb, Wl1, bl1, Wr1, br1,
                        Wl2, bl2, Wr2, br2, wbT, bias, We1, att1, be1, bo1, g1, beta1,
                        We2, att2, be2, bo2, g2, beta2, Wo, bout, wep, prm);
    else
        prep_impl<false>(off0, bsum, deg, rankd, dbase, perm, offF, ei, rank, esrc,
                         x, node_idx, emb, W_in, b_in, zb, Wl1, bl1, Wr1, br1,
                         Wl2, bl2, Wr2, br2, wbT, bias, We1, att1, be1, bo1, g1, beta1,
                         We2, att2, be2, bo2, g2, beta2, Wo, bout, wep, prm);
}

// ---- MFMA projection body, SWAPPED operands: D[channel][node] = W·zb^T.
// Each lane holds 4 CONSECUTIVE channels of one node -> single 8B store.
// 64 nodes per virtual block, weight fragments loaded once per wave.
__device__ __forceinline__ void projmm_body(int vb, const bf16* __restrict__ zb,
                                            const bf16* __restrict__ wbT,
                                            const float* __restrict__ bias,
                                            bf16* __restrict__ xl, bf16* __restrict__ xr) {
    int wave = threadIdx.x >> 6, lane = threadIdx.x & 63;
    int n0 = wave * 64;             // output-channel base (0..255)
    int l15 = lane & 15, q = lane >> 4;
    bshort8 afr[4][4];  // [j][s]: A rows = channels n0+j*16+l15, k-slice s*32+q*8
    #pragma unroll
    for (int j = 0; j < 4; j++)
        #pragma unroll
        for (int s = 0; s < 4; s++)
            afr[j][s] = *(const bshort8*)(wbT + ((n0 + j * 16 + l15) << 7) + s * 32 + q * 8);
    float4 bias4[4];
    #pragma unroll
    for (int j = 0; j < 4; j++) bias4[j] = *(const float4*)(bias + n0 + j * 16 + q * 4);
    bf16* dst = (n0 < HIDD) ? xl : xr;
    int cbase = (n0 & (HIDD - 1)) + q * 4;
    int nodeBase = vb * 64;
    #pragma unroll
    for (int mt = 0; mt < 4; mt++) {
        int node = nodeBase + mt * 16 + l15;
        const bf16* brow = zb + (node << 7) + q * 8;  // OOB rows read into xl region (safe)
        bshort8 bfrag[4];
        #pragma unroll
        for (int s = 0; s < 4; s++) bfrag[s] = *(const bshort8*)(brow + s * 32);
        floatx4 acc0 = {0.f, 0.f, 0.f, 0.f}, acc1 = acc0, acc2 = acc0, acc3 = acc0;
        #pragma unroll
        for (int s = 0; s < 4; s++) {
            acc0 = __builtin_amdgcn_mfma_f32_16x16x32_bf16(afr[0][s], bfrag[s], acc0, 0, 0, 0);
            acc1 = __builtin_amdgcn_mfma_f32_16x16x32_bf16(afr[1][s], bfrag[s], acc1, 0, 0, 0);
            acc2 = __builtin_amdgcn_mfma_f32_16x16x32_bf16(afr[2][s], bfrag[s], acc2, 0, 0, 0);
            acc3 = __builtin_amdgcn_mfma_f32_16x16x32_bf16(afr[3][s], bfrag[s], acc3, 0, 0, 0);
        }
        if (node < NN) {
            floatx4 accs[4] = {acc0, acc1, acc2, acc3};
            #pragma unroll
            for (int j = 0; j < 4; j++) {
                float4 bv = bias4[j];
                uint2 pk;
                pk.x = (unsigned int)f2bu(accs[j][0] + bv.x) |
                       ((unsigned int)f2bu(accs[j][1] + bv.y) << 16);
                pk.y = (unsigned int)f2bu(accs[j][2] + bv.z) |
                       ((unsigned int)f2bu(accs[j][3] + bv.w) << 16);
                *(uint2*)(dst + (node << 7) + cbase + j * 16) = pk;
            }
        }
    }
}
__global__ __launch_bounds__(256) void k_projmm(const bf16* __restrict__ zb,
                                                const bf16* __restrict__ wbT,
                                                const float* __restrict__ bias,
                                                bf16* __restrict__ xl, bf16* __restrict__ xr) {
    projmm_body(blockIdx.x, zb, wbT, bias, xl, xr);
}

// ---- fill PHASE 2 (+ layer-1 projmm, merged launch): sequential slot scan,
// in-place esrc transform (edge-id -> src-id) + sequential ea8 write from
// random ea gather (L3 absorbs gathers; avoids cross-XCD scatter-write RMW).
template <bool F32>
__device__ void f2_impl(int* __restrict__ esrc, uint4* __restrict__ ea8,
                        const int* __restrict__ ei, const void* ea) {
    int slot = blockIdx.x * 256 + threadIdx.x;
    if (slot >= NE) return;
    if (slot < 16) {
        esrc[NE + slot] = 0;
        uint4 z; z.x = 0; z.y = 0; z.z = 0; z.w = 0;
        ea8[NE + slot] = z;
    }
    int e = esrc[slot];        // phase-1 edge id
    esrc[slot] = ei[e];        // in-place: now src node id
    uint4 v;
    if constexpr (F32) {
        const float4* ef = (const float4*)ea;
        float4 f0 = ef[2 * e], f1 = ef[2 * e + 1];
        v.x = (unsigned int)f2bu(f0.x) | ((unsigned int)f2bu(f0.y) << 16);
        v.y = (unsigned int)f2bu(f0.z) | ((unsigned int)f2bu(f0.w) << 16);
        v.z = (unsigned int)f2bu(f1.x) | ((unsigned int)f2bu(f1.y) << 16);
        v.w = (unsigned int)f2bu(f1.z) | ((unsigned int)f2bu(f1.w) << 16);
    } else {
        v = ((const uint4*)ea)[e];  // bf16 pairs already packed
    }
    ea8[slot] = v;
}
__global__ __launch_bounds__(256) void k_f2pm(const int* cnt, int* esrc, uint4* ea8,
                                              const int* ei, const void* ea,
                                              const bf16* zb, const bf16* wbT,
                                              const float* bias, bf16* xl, bf16* xr) {
    if (blockIdx.x < FILLB) {
        if (is_f32(cnt)) f2_impl<true>(esrc, ea8, ei, ea);
        else             f2_impl<false>(esrc, ea8, ei, ea);
    } else {
        projmm_body(blockIdx.x - FILLB, zb, wbT, bias, xl, xr);
    }
}

// ---- per-edge compute body (half-wave: 32 lanes, 4 ch/lane, 8-lane head groups)
__device__ __forceinline__ void edge_body(uint4 eu, uint2 xu, const unsigned int (*wp)[4],
                                          const float* base, const f32x2* at2,
                                          float mask, f32x2* acc, float& den) {
    f32x2 xv0, xv1;
    xv0.x = __uint_as_float(xu.x << 16); xv0.y = __uint_as_float(xu.x & 0xffff0000u);
    xv1.x = __uint_as_float(xu.y << 16); xv1.y = __uint_as_float(xu.y & 0xffff0000u);
    f32x2 e01, e23;
    {
        float c0 = base[0];
        c0 = dot2bf(eu.x, wp[0][0], c0);
        c0 = dot2bf(eu.y, wp[1][0], c0);
        c0 = dot2bf(eu.z, wp[2][0], c0);
        c0 = dot2bf(eu.w, wp[3][0], c0);
        float c1 = base[1];
        c1 = dot2bf(eu.x, wp[0][1], c1);
        c1 = dot2bf(eu.y, wp[1][1], c1);
        c1 = dot2bf(eu.z, wp[2][1], c1);
        c1 = dot2bf(eu.w, wp[3][1], c1);
        e01.x = c0; e01.y = c1;
        float c2 = base[2];
        c2 = dot2bf(eu.x, wp[0][2], c2);
        c2 = dot2bf(eu.y, wp[1][2], c2);
        c2 = dot2bf(eu.z, wp[2][2], c2);
        c2 = dot2bf(eu.w, wp[3][2], c2);
        float c3 = base[3];
        c3 = dot2bf(eu.x, wp[0][3], c3);
        c3 = dot2bf(eu.y, wp[1][3], c3);
        c3 = dot2bf(eu.z, wp[2][3], c3);
        c3 = dot2bf(eu.w, wp[3][3], c3);
        e23.x = c2; e23.y = c3;
    }
    f32x2 s0 = xv0 + e01;
    f32x2 s1 = xv1 + e23;
    s0 = __builtin_elementwise_max(s0, s0 * 0.2f);  // leakyrelu (packed)
    s1 = __builtin_elementwise_max(s1, s1 * 0.2f);
    f32x2 lsv = s0 * at2[0] + s1 * at2[1];
    float ls = lsv.x + lsv.y;
    ls += __shfl_xor(ls, 1);
    ls += __shfl_xor(ls, 2);
    ls += __shfl_xor(ls, 4);   // 8-lane head group = 32 channels
    float ex = exp2f(ls) * mask;  // att pre-scaled by log2e
    acc[0] += ex * xv0;
    acc[1] += ex * xv1;
    den += ex;
}

// ---- fused GAT layer: 2 nodes per wave (degree-matched via global-sort perm),
// 4 ch/lane, 2-edge ILP with three-level rotating prefetch (xl TWO iters ahead,
// esrc/ea8 three iters ahead; pad slots NE..NE+15), barrier-free LN.
// All per-layer params pre-packed (wep: bf16-pair edge weights; P: f32 vectors).
// LAST fuses the output head. [NPG=4 regressed (r7: occ 46->31%); keep 1.]
template <bool LAST>
__device__ __forceinline__ void gat_impl(const int* __restrict__ perm,
                         const int* __restrict__ off, const int* __restrict__ esrc,
                         const uint4* __restrict__ ea8,
                         const unsigned int* __restrict__ wep,
                         const float* __restrict__ P,
                         const bf16* __restrict__ xl, const bf16* __restrict__ xr,
                         bf16* __restrict__ zb, void* out, bool f32out) {
    int wave = threadIdx.x >> 6;
    int half = (threadIdx.x >> 5) & 1;
    int lane5 = threadIdx.x & 31;
    int n = perm[blockIdx.x * 8 + wave * 2 + half];
    int c0 = lane5 << 2;  // 4 channels c0..c0+3 ; head = lane5>>3
    unsigned int wp[4][4];
    {
        const uint4* w4 = (const uint4*)(wep + lane5 * 16);
        uint4 wa = w4[0], wb = w4[1], wc = w4[2], wd = w4[3];
        wp[0][0] = wa.x; wp[0][1] = wa.y; wp[0][2] = wa.z; wp[0][3] = wa.w;
        wp[1][0] = wb.x; wp[1][1] = wb.y; wp[1][2] = wb.z; wp[1][3] = wb.w;
        wp[2][0] = wc.x; wp[2][1] = wc.y; wp[2][2] = wc.z; wp[2][3] = wc.w;
        wp[3][0] = wd.x; wp[3][1] = wd.y; wp[3][2] = wd.z; wp[3][3] = wd.w;
    }
    float4 atv = *(const float4*)(P + c0);
    f32x2 at2[2];
    at2[0].x = atv.x; at2[0].y = atv.y;
    at2[1].x = atv.z; at2[1].y = atv.w;
    float4 bev = *(const float4*)(P + 128 + c0);
    uint2 xru = *(const uint2*)(xr + (n << 7) + c0);
    float base[4];
    base[0] = bev.x + __uint_as_float(xru.x << 16);
    base[1] = bev.y + __uint_as_float(xru.x & 0xffff0000u);
    base[2] = bev.z + __uint_as_float(xru.y << 16);
    base[3] = bev.w + __uint_as_float(xru.y & 0xffff0000u);
    int lo = off[n], hi = off[n + 1];
    f32x2 accA[2] = {{0.f, 0.f}, {0.f, 0.f}}, accB[2] = {{0.f, 0.f}, {0.f, 0.f}};
    float denA = 0.f, denB = 0.f;
    if (lo < hi) {
        // pipeline: edges i,i+1 fully resident; xl resident for i+2,i+3;
        // meta (esrc/ea8) resident for i+4,i+5. In-loop: issue xl for i+4,
        // meta for i+6. All overruns land in pad slots NE..NE+15.
        int sA = esrc[lo],      sB = esrc[lo + 1];
        uint4 eA = ea8[lo],     eB = ea8[lo + 1];
        int snA = esrc[lo + 2], snB = esrc[lo + 3];
        uint4 enA = ea8[lo + 2], enB = ea8[lo + 3];
        int s2A = esrc[lo + 4], s2B = esrc[lo + 5];
        uint4 e2A = ea8[lo + 4], e2B = ea8[lo + 5];
        uint2 xA = *(const uint2*)(xl + (sA << 7) + c0);
        uint2 xB = *(const uint2*)(xl + (sB << 7) + c0);
        uint2 xnA = *(const uint2*)(xl + (snA << 7) + c0);
        uint2 xnB = *(const uint2*)(xl + (snB << 7) + c0);
        for (int i = lo; i < hi; i += 2) {
            uint2 x2A = *(const uint2*)(xl + (s2A << 7) + c0);  // xl for i+4/i+5
            uint2 x2B = *(const uint2*)(xl + (s2B << 7) + c0);
            int s3A = esrc[i + 6],  s3B = esrc[i + 7];           // meta for i+6/i+7
            uint4 e3A = ea8[i + 6], e3B = ea8[i + 7];
            edge_body(eA, xA, wp, base, at2, 1.f, accA, denA);
            float mB = (i + 1 < hi) ? 1.f : 0.f;
            edge_body(eB, xB, wp, base, at2, mB, accB, denB);
            eA = enA; enA = e2A; e2A = e3A;
            eB = enB; enB = e2B; e2B = e3B;
            xA = xnA; xnA = x2A;
            xB = xnB; xnB = x2B;
            s2A = s3A; s2B = s3B;
        }
        accA[0] += accB[0];
        accA[1] += accB[1];
        denA += denB;
    }
    float inv = (denA > 0.f) ? 1.0f / denA : 0.f;
    uint2 zu = *(const uint2*)(zb + (n << 7) + c0);
    float zv[4];
    zv[0] = __uint_as_float(zu.x << 16);
    zv[1] = __uint_as_float(zu.x & 0xffff0000u);
    zv[2] = __uint_as_float(zu.y << 16);
    zv[3] = __uint_as_float(zu.y & 0xffff0000u);
    float accf[4] = {accA[0].x, accA[0].y, accA[1].x, accA[1].y};
    float4 bo4 = *(const float4*)(P + 256 + c0);
    float bov[4] = {bo4.x, bo4.y, bo4.z, bo4.w};
    float v[4];
    float s = 0.f;
    #pragma unroll
    for (int j = 0; j < 4; j++) {
        float hv = fmaxf(accf[j] * inv + bov[j], 0.f);
        v[j] = zv[j] + hv;
        s += v[j];
    }
    #pragma unroll
    for (int m = 16; m; m >>= 1) s += __shfl_xor(s, m);  // 32-lane sum
    float mu = s * (1.f / HIDD);
    float s2v = 0.f;
    float dv[4];
    #pragma unroll
    for (int j = 0; j < 4; j++) { dv[j] = v[j] - mu; s2v += dv[j] * dv[j]; }
    #pragma unroll
    for (int m = 16; m; m >>= 1) s2v += __shfl_xor(s2v, m);
    float rs = rsqrtf(s2v * (1.f / HIDD) + 1e-5f);
    float4 g4 = *(const float4*)(P + 384 + c0);
    float4 bt4 = *(const float4*)(P + 512 + c0);
    float gv[4] = {g4.x, g4.y, g4.z, g4.w};
    float btv[4] = {bt4.x, bt4.y, bt4.z, bt4.w};
    float o[4];
    #pragma unroll
    for (int j = 0; j < 4; j++)
        o[j] = dv[j] * rs * gv[j] + btv[j];
    if constexpr (!LAST) {
        uint2 pk;
        pk.x = (unsigned int)f2bu(o[0]) | ((unsigned int)f2bu(o[1]) << 16);
        pk.y = (unsigned int)f2bu(o[2]) | ((unsigned int)f2bu(o[3]) << 16);
        *(uint2*)(zb + (n << 7) + c0) = pk;
    } else {
        float4 wo4 = *(const float4*)(P + 640 + c0);
        float wov[4] = {wo4.x, wo4.y, wo4.z, wo4.w};
        float po = 0.f;
        #pragma unroll
        for (int j = 0; j < 4; j++) po += o[j] * wov[j];
        #pragma unroll
        for (int m = 16; m; m >>= 1) po += __shfl_xor(po, m);
        if (lane5 == 0) {
            float r = po + P[768];
            if (f32out) ((float*)out)[n] = r;
            else        ((bf16*)out)[n] = __float2bfloat16(r);
        }
    }
}
__global__ void k_gat(const int* perm, const int* off, const int* esrc,
                      const uint4* ea8, const unsigned int* wep, const float* prm,
                      const bf16* xl, const bf16* xr, bf16* zb) {
    gat_impl<false>(perm, off, esrc, ea8, wep, prm, xl, xr, zb, nullptr, false);
}
__global__ void k_gat_last(const int* cnt, const int* perm, const int* off, const int* esrc,
                           const uint4* ea8, const unsigned int* wep, const float* prm,
                           const bf16* xl, const bf16* xr, bf16* zb, void* out) {
    gat_impl<true>(perm, off, esrc, ea8, wep, prm, xl, xr, zb, out, is_f32(cnt));
}

extern "C" void kernel_launch(void* const* d_in, const int* in_sizes, int n_in,
                              void* d_out, int out_size, void* d_ws, size_t ws_size,
                              hipStream_t stream) {
    const void* x        = d_in[0];
    const int*  node_idx = (const int*)d_in[1];
    const int*  ei       = (const int*)d_in[2];
    const void* ea       = d_in[3];
    const void* emb      = d_in[4];
    const void* W_in     = d_in[5];
    const void* b_in     = d_in[6];
    const void* Wl1 = d_in[7];  const void* bl1 = d_in[8];
    const void* Wr1 = d_in[9];  const void* br1 = d_in[10];
    const void* We1 = d_in[11]; const void* be1 = d_in[12];
    const void* att1 = d_in[13]; const void* bo1 = d_in[14];
    const void* Wl2 = d_in[15]; const void* bl2 = d_in[16];
    const void* Wr2 = d_in[17]; const void* br2 = d_in[18];
    const void* We2 = d_in[19]; const void* be2 = d_in[20];
    const void* att2 = d_in[21]; const void* bo2 = d_in[22];
    const void* g1 = d_in[23]; const void* beta1 = d_in[24];
    const void* g2 = d_in[25]; const void* beta2 = d_in[26];
    const void* W_out = d_in[27]; const void* b_out = d_in[28];

    // workspace (~55 MB), 16B-aligned sections:
    int*   cnt   = (int*)d_ws;                             // 64 ints
    uint4* ea8   = (uint4*)((char*)d_ws + 256);            // NE+16 (pad slots at NE..)
    bf16*  zb    = (bf16*)(ea8 + NE + 16);                 // NN*HIDD
    bf16*  xl    = zb + NN * HIDD;                         // NN*HIDD
    bf16*  xr    = xl + NN * HIDD;                         // NN*HIDD
    bf16*  wbT   = xr + NN * HIDD;                         // 2*256*128
    float* bias  = (float*)(wbT + 2 * 256 * HIDD);         // 512
    unsigned int* wep = (unsigned int*)(bias + 512);       // 2*512
    float* prm   = (float*)(wep + 1024);                   // 2*PRMF
    int*   off0  = (int*)(prm + 2 * PRMF);                 // NN+1 (partial scan)
    int*   offF  = off0 + NN + 1;                          // NN+1 (final CSR offsets)
    int*   deg   = offF + NN + 1;                          // NN
    int*   rank  = deg + NN;                               // NE
    int*   rankd = rank + NE;                              // NN
    int*   perm  = rankd + NN;                             // NN
    int*   esrc  = perm + NN;                              // NE+16 (pads at NE..)
    int*   bsum  = esrc + NE + 16;                         // 256
    int*   dcnt  = bsum + 256;                             // 80 (ticket at [64])
    int*   dbase = dcnt + 80;                              // 64

    int nhalf = in_sizes[0] < 16384 ? in_sizes[0] : 16384;
    k_detinit<<<NB_SCAN + 1, 256, 0, stream>>>((const unsigned short*)x, nhalf, cnt, deg, dcnt);
    k_hist<<<FILLB, 256, 0, stream>>>(ei, deg, rank);
    k_scan12<<<NB_SCAN, 256, 0, stream>>>(deg, off0, bsum, dcnt, dbase, rankd);
    k_prep<<<NB_SCAN + FILLB + BZB + WPB + 2, 256, 0, stream>>>(
        cnt, off0, bsum, deg, rankd, dbase, perm, offF, ei, rank, esrc,
        x, node_idx, emb, W_in, b_in, zb,
        Wl1, bl1, Wr1, br1, Wl2, bl2, Wr2, br2, wbT, bias,
        We1, att1, be1, bo1, g1, beta1,
        We2, att2, be2, bo2, g2, beta2,
        W_out, b_out, wep, prm);

    // ---- fill phase 2 + layer-1 projection (merged launch) ----
    k_f2pm<<<FILLB + PJB, 256, 0, stream>>>(cnt, esrc, ea8, ei, ea, zb, wbT, bias, xl, xr);
    // ---- layer 1 ----
    k_gat<<<NN / 8, 256, 0, stream>>>(perm, offF, esrc, ea8, wep, prm, xl, xr, zb);

    // ---- layer 2 ----
    k_projmm<<<PJB, 256, 0, stream>>>(zb, wbT + 256 * HIDD, bias + 256, xl, xr);
    k_gat_last<<<NN / 8, 256, 0, stream>>>(cnt, perm, offF, esrc, ea8, wep + 512, prm + PRMF,
                                           xl, xr, zb, d_out);
}